// Round 12
// baseline (1705.905 us; speedup 1.0000x reference)
//
#include <hip/hip_runtime.h>
#include <hip/hip_bf16.h>
#include <math.h>
#include <string.h>

#define HID 32
#define HS_ROWS 32               // hsum partial rows (spread atomic contention)
#define COLBUF 3072              // mlp_fused col slice; 32 nodes, mean 2048 (guarded)
#define COLBUF0 6144             // mlp0 col slice; 64 nodes, mean 4096 (guarded)
typedef unsigned short u16;
typedef unsigned char u8;
typedef float f32x2 __attribute__((ext_vector_type(2)));

// ---------- fp8 e4m3 helpers (OCP; non-negative activations) ----------
__device__ inline float e42f_sw(unsigned b) {
    unsigned u = (b & 0x7fu) << 20;
    float f; memcpy(&f, &u, 4);
    return f * 0x1p120f;
}
__device__ inline unsigned f2e4_sw(float f) {
    f = fminf(f, 448.f);
    float y = f * 0x1p-120f;
    unsigned r; memcpy(&r, &y, 4);
    r = r + 0x7FFFFu + ((r >> 20) & 1u);
    return (r >> 20) & 0x7fu;
}
// accumulate 4 e4m3 (one u32) into a[0..3] — HW cvt when available (R9 win)
__device__ inline void acc_e4(float* a, unsigned w) {
#if __has_builtin(__builtin_amdgcn_cvt_pk_f32_fp8)
    f32x2 lo = __builtin_amdgcn_cvt_pk_f32_fp8(w, false);   // bytes 0,1
    f32x2 hi = __builtin_amdgcn_cvt_pk_f32_fp8(w, true);    // bytes 2,3
    a[0] += lo.x; a[1] += lo.y; a[2] += hi.x; a[3] += hi.y;
#else
    a[0] += e42f_sw(w);
    a[1] += e42f_sw(w >> 8);
    a[2] += e42f_sw(w >> 16);
    a[3] += e42f_sw(w >> 24);
#endif
}
__device__ inline unsigned pack_e4(float o0, float o1, float o2, float o3) {
#if __has_builtin(__builtin_amdgcn_cvt_pk_fp8_f32)
    unsigned pw = (unsigned)__builtin_amdgcn_cvt_pk_fp8_f32(
        fminf(o0, 448.f), fminf(o1, 448.f), 0, false);
    pw = (unsigned)__builtin_amdgcn_cvt_pk_fp8_f32(
        fminf(o2, 448.f), fminf(o3, 448.f), pw, true);
    return pw;
#else
    return f2e4_sw(o0) | (f2e4_sw(o1) << 8) | (f2e4_sw(o2) << 16) | (f2e4_sw(o3) << 24);
#endif
}

// ---------------- zero ----------------
__global__ void zero_kernel(float* __restrict__ p, int n) {
    int i = blockIdx.x * blockDim.x + threadIdx.x;
    if (i < n) p[i] = 0.f;
}
__global__ void zero_int(int* __restrict__ p, int n) {
    int i = blockIdx.x * blockDim.x + threadIdx.x;
    if (i < n) p[i] = 0;
}

// ---------------- direct CSR build (R12): hist -> scan -> scatter ----------------
// fp8 table is L2-resident since R7, so gather order no longer matters -> no sort
// needed. Replaces partition(56us)+scan+sort(~40us) with hist+3 tiny scans+scatter.
__global__ void hist_edges(const int* __restrict__ dst, int* __restrict__ cnt, int E) {
    int e = (blockIdx.x * blockDim.x + threadIdx.x) * 4;
    if (e + 3 < E) {
        int4 D = *(const int4*)(dst + e);
        atomicAdd(&cnt[D.x], 1);
        atomicAdd(&cnt[D.y], 1);
        atomicAdd(&cnt[D.z], 1);
        atomicAdd(&cnt[D.w], 1);
    } else {
        for (int j = e; j < E && j < e + 4; j++) atomicAdd(&cnt[dst[j]], 1);
    }
}

// scan stage A: per-block (1024 counts) sums
__global__ void scan_partial(const int* __restrict__ cnt, int* __restrict__ bsum, int N) {
    __shared__ int wsums[4];
    int t = threadIdx.x, wid = t >> 6, lane = t & 63;
    int base = blockIdx.x * 1024 + t * 4;
    int s = 0;
#pragma unroll
    for (int j = 0; j < 4; j++) { int idx = base + j; if (idx < N) s += cnt[idx]; }
#pragma unroll
    for (int off = 1; off < 64; off <<= 1) s += __shfl_xor(s, off, 64);
    if (lane == 0) wsums[wid] = s;
    __syncthreads();
    if (t == 0) bsum[blockIdx.x] = wsums[0] + wsums[1] + wsums[2] + wsums[3];
}

// scan stage B: exclusive scan of nb block sums (nb <= 1024), in place; total -> rowptr[N]
__global__ void scan_blocksums(int* __restrict__ bsum, int* __restrict__ rowptr,
                               int nb, int N) {
    __shared__ int wsums[4];
    int t = threadIdx.x, wid = t >> 6, lane = t & 63;
    int b0 = 4 * t;
    int v[4]; int s = 0;
#pragma unroll
    for (int j = 0; j < 4; j++) { int b = b0 + j; v[j] = (b < nb) ? bsum[b] : 0; s += v[j]; }
    int incl = s;
#pragma unroll
    for (int off = 1; off < 64; off <<= 1) {
        int u = __shfl_up(incl, off, 64);
        if (lane >= off) incl += u;
    }
    if (lane == 63) wsums[wid] = incl;
    __syncthreads();
    int woff = 0;
#pragma unroll
    for (int w = 0; w < 4; w++) if (w < wid) woff += wsums[w];
    int excl = woff + incl - s;
    int runx = excl;
#pragma unroll
    for (int j = 0; j < 4; j++) {
        int b = b0 + j;
        if (b < nb) bsum[b] = runx;
        runx += v[j];
    }
    if (t == 0) rowptr[N] = wsums[0] + wsums[1] + wsums[2] + wsums[3];
}

// scan stage C: block-local exclusive scan + base -> rowptr & scatter cursors
__global__ void scan_write(const int* __restrict__ cnt, const int* __restrict__ bsum,
                           int* __restrict__ rowptr, int* __restrict__ curp, int N) {
    __shared__ int wsums[4];
    int t = threadIdx.x, wid = t >> 6, lane = t & 63;
    int base = blockIdx.x * 1024 + t * 4;
    int v[4]; int s = 0;
#pragma unroll
    for (int j = 0; j < 4; j++) { int idx = base + j; v[j] = (idx < N) ? cnt[idx] : 0; s += v[j]; }
    int incl = s;
#pragma unroll
    for (int off = 1; off < 64; off <<= 1) {
        int u = __shfl_up(incl, off, 64);
        if (lane >= off) incl += u;
    }
    if (lane == 63) wsums[wid] = incl;
    __syncthreads();
    int woff = 0;
#pragma unroll
    for (int w = 0; w < 4; w++) if (w < wid) woff += wsums[w];
    int excl = woff + incl - s + bsum[blockIdx.x];
    int runx = excl;
#pragma unroll
    for (int j = 0; j < 4; j++) {
        int idx = base + j;
        if (idx < N) { rowptr[idx] = runx; curp[idx] = runx; runx += v[j]; }
    }
}

__global__ void scatter_edges(const int* __restrict__ src, const int* __restrict__ dst,
                              int* __restrict__ curp, int* __restrict__ col, int E) {
    int e = (blockIdx.x * blockDim.x + threadIdx.x) * 4;
    if (e + 3 < E) {
        int4 S = *(const int4*)(src + e);
        int4 D = *(const int4*)(dst + e);
        col[atomicAdd(&curp[D.x], 1)] = S.x;
        col[atomicAdd(&curp[D.y], 1)] = S.y;
        col[atomicAdd(&curp[D.z], 1)] = S.z;
        col[atomicAdd(&curp[D.w], 1)] = S.w;
    } else {
        for (int j = e; j < E && j < e + 4; j++)
            col[atomicAdd(&curp[dst[j]], 1)] = src[j];
    }
}

// ---------------- layer 0 fused: gather(d=1) + MLP -> fp8 out ----------------
__global__ void mlp0_fused(const int* __restrict__ rowptr, const int* __restrict__ col,
                           const float* __restrict__ x0,
                           const float* __restrict__ W1, const float* __restrict__ b1,
                           const float* __restrict__ W2, const float* __restrict__ b2,
                           u8* __restrict__ out, int n) {
    __shared__ float sW1[HID], sb1[HID], sW2[HID * HID], sb2[HID];
    __shared__ int colbuf[COLBUF0];
    int t = threadIdx.x;
    if (t < HID) { sW1[t] = W1[t]; sb1[t] = b1[t]; sb2[t] = b2[t]; }
    for (int i = t; i < HID * HID; i += blockDim.x) sW2[i] = W2[i];

    int firstNode = blockIdx.x * 64;
    int lastNode  = firstNode + 64; if (lastNode > n) lastNode = n;
    int blockStart = (firstNode < n) ? rowptr[firstNode] : 0;
    int blockEnd   = (firstNode < n) ? rowptr[lastNode] : 0;
    int stagedCnt = blockEnd - blockStart; if (stagedCnt > COLBUF0) stagedCnt = COLBUF0;
    for (int i = t; i < stagedCnt; i += 256) colbuf[i] = col[blockStart + i];
    __syncthreads();

    int node = firstNode + (t >> 2);
    int q    = t & 3;
    int lane = t & 63;
    int base = lane & ~3;
    bool active = node < n;

    float s = 0.f;
    if (active) {
        int beg = rowptr[node], end = rowptr[node + 1];
        int jSplit = blockStart + stagedCnt; if (jSplit > end) jSplit = end;
        int j = beg + q;
        for (; j + 12 < jSplit; j += 16) {
            int c0 = colbuf[j - blockStart];
            int c1 = colbuf[j + 4 - blockStart];
            int c2 = colbuf[j + 8 - blockStart];
            int c3 = colbuf[j + 12 - blockStart];
            s += x0[c0]; s += x0[c1]; s += x0[c2]; s += x0[c3];
        }
        for (; j < jSplit; j += 4) s += x0[colbuf[j - blockStart]];
        for (; j < end; j += 4) s += x0[col[j]];
    }
    s += __shfl_xor(s, 1, 64);
    s += __shfl_xor(s, 2, 64);
    float v = active ? (x0[node] + s) : 0.f;

    float h[8];
#pragma unroll
    for (int i = 0; i < 8; i++) h[i] = fmaxf(fmaf(v, sW1[q * 8 + i], sb1[q * 8 + i]), 0.f);
    float o[8];
#pragma unroll
    for (int i = 0; i < 8; i++) o[i] = sb2[q * 8 + i];
#pragma unroll
    for (int k = 0; k < HID; k++) {
        float hk = __shfl(h[k & 7], base | (k >> 3), 64);
#pragma unroll
        for (int i = 0; i < 8; i++) o[i] = fmaf(hk, sW2[k * HID + q * 8 + i], o[i]);
    }
    if (active) {
        unsigned w0 = pack_e4(fmaxf(o[0], 0.f), fmaxf(o[1], 0.f),
                              fmaxf(o[2], 0.f), fmaxf(o[3], 0.f));
        unsigned w1 = pack_e4(fmaxf(o[4], 0.f), fmaxf(o[5], 0.f),
                              fmaxf(o[6], 0.f), fmaxf(o[7], 0.f));
        uint2 pk = make_uint2(w0, w1);
        *(uint2*)(out + ((size_t)node << 5) + (q << 3)) = pk;
    }
}

// ---------------- hidden layer fused: fp8 gather + MLP, 8 lanes/node, 32 nodes/block ----
template <bool REDUCE>
__global__ void mlp_fused(const int* __restrict__ rowptr, const int* __restrict__ col,
                          const u8* __restrict__ xin,
                          const float* __restrict__ W1, const float* __restrict__ b1,
                          const float* __restrict__ W2, const float* __restrict__ b2,
                          u8* __restrict__ xout, float* __restrict__ hsum, int n) {
    __shared__ float sW1[HID * HID], sb1[HID], sW2[HID * HID], sb2[HID];
    __shared__ int colbuf[COLBUF];
    __shared__ float red[4][HID];
    int t = threadIdx.x;
    for (int i = t; i < HID * HID; i += blockDim.x) { sW1[i] = W1[i]; sW2[i] = W2[i]; }
    if (t < HID) { sb1[t] = b1[t]; sb2[t] = b2[t]; }

    int firstNode = blockIdx.x * 32;
    int lastNode  = firstNode + 32; if (lastNode > n) lastNode = n;
    int blockStart = (firstNode < n) ? rowptr[firstNode] : 0;
    int blockEnd   = (firstNode < n) ? rowptr[lastNode] : 0;
    int stagedCnt = blockEnd - blockStart; if (stagedCnt > COLBUF) stagedCnt = COLBUF;
    for (int i = t; i < stagedCnt; i += 256) colbuf[i] = col[blockStart + i];
    __syncthreads();

    int node = firstNode + (t >> 3);
    int q    = t & 7;            // lane owns features [q*4, q*4+4)
    int lane = t & 63;
    int base = lane & ~7;
    bool active = node < n;

    float va[4];
#pragma unroll
    for (int i = 0; i < 4; i++) va[i] = 0.f;
    if (active) {
        int beg = rowptr[node], end = rowptr[node + 1];
        const u8* xq = xin + (q << 2);
        float a0[4], a1[4], a2[4], a3[4];
#pragma unroll
        for (int i = 0; i < 4; i++) a0[i] = a1[i] = a2[i] = a3[i] = 0.f;
        {   // self term (eps = 0)
            unsigned w = *(const unsigned*)(xq + ((size_t)node << 5));
            acc_e4(a0, w);
        }
        int jSplit = blockStart + stagedCnt; if (jSplit > end) jSplit = end;
        int j = beg;
        for (; j + 8 <= jSplit; j += 8) {
            int lj = j - blockStart;
            int c0 = colbuf[lj+0], c1 = colbuf[lj+1], c2 = colbuf[lj+2], c3 = colbuf[lj+3];
            int c4 = colbuf[lj+4], c5 = colbuf[lj+5], c6 = colbuf[lj+6], c7 = colbuf[lj+7];
            unsigned w0 = *(const unsigned*)(xq + ((size_t)c0 << 5));
            unsigned w1 = *(const unsigned*)(xq + ((size_t)c1 << 5));
            unsigned w2 = *(const unsigned*)(xq + ((size_t)c2 << 5));
            unsigned w3 = *(const unsigned*)(xq + ((size_t)c3 << 5));
            unsigned w4 = *(const unsigned*)(xq + ((size_t)c4 << 5));
            unsigned w5 = *(const unsigned*)(xq + ((size_t)c5 << 5));
            unsigned w6 = *(const unsigned*)(xq + ((size_t)c6 << 5));
            unsigned w7 = *(const unsigned*)(xq + ((size_t)c7 << 5));
            acc_e4(a0, w0); acc_e4(a1, w1); acc_e4(a2, w2); acc_e4(a3, w3);
            acc_e4(a0, w4); acc_e4(a1, w5); acc_e4(a2, w6); acc_e4(a3, w7);
        }
        for (; j < jSplit; j++) {
            unsigned w = *(const unsigned*)(xq + ((size_t)colbuf[j - blockStart] << 5));
            acc_e4(a0, w);
        }
        for (; j < end; j++) {   // colbuf overflow fallback (statistically unreachable)
            unsigned w = *(const unsigned*)(xq + ((size_t)col[j] << 5));
            acc_e4(a0, w);
        }
#pragma unroll
        for (int i = 0; i < 4; i++) va[i] = (a0[i] + a1[i]) + (a2[i] + a3[i]);
    }

    float h[4];
#pragma unroll
    for (int i = 0; i < 4; i++) h[i] = sb1[q * 4 + i];
#pragma unroll
    for (int k = 0; k < HID; k++) {
        float vk = __shfl(va[k & 3], base | (k >> 2), 64);
#pragma unroll
        for (int i = 0; i < 4; i++) h[i] = fmaf(vk, sW1[k * HID + q * 4 + i], h[i]);
    }
#pragma unroll
    for (int i = 0; i < 4; i++) h[i] = fmaxf(h[i], 0.f);

    float o[4];
#pragma unroll
    for (int i = 0; i < 4; i++) o[i] = sb2[q * 4 + i];
#pragma unroll
    for (int k = 0; k < HID; k++) {
        float hk = __shfl(h[k & 3], base | (k >> 2), 64);
#pragma unroll
        for (int i = 0; i < 4; i++) o[i] = fmaf(hk, sW2[k * HID + q * 4 + i], o[i]);
    }
#pragma unroll
    for (int i = 0; i < 4; i++) o[i] = fmaxf(o[i], 0.f);

    if (REDUCE) {
        if (!active) {
#pragma unroll
            for (int i = 0; i < 4; i++) o[i] = 0.f;
        }
#pragma unroll
        for (int i = 0; i < 4; i++) {   // sum the 8 nodes of this wave (lane bits 3..5)
            float v = o[i];
            v += __shfl_xor(v, 8, 64);
            v += __shfl_xor(v, 16, 64);
            v += __shfl_xor(v, 32, 64);
            o[i] = v;
        }
        int wid = t >> 6;
        if (lane < 8) {
#pragma unroll
            for (int i = 0; i < 4; i++) red[wid][lane * 4 + i] = o[i];
        }
        __syncthreads();
        if (t < HID) {
            float s = red[0][t] + red[1][t] + red[2][t] + red[3][t];
            atomicAdd(&hsum[(blockIdx.x & (HS_ROWS - 1)) * (2 * HID) + t], s);
        }
    } else if (active) {
        unsigned pw = pack_e4(o[0], o[1], o[2], o[3]);
        *(unsigned*)(xout + ((size_t)node << 5) + (q << 2)) = pw;
    }
}

// ---------------- head ----------------
__global__ void head_kernel(const float* __restrict__ hsumP,
                            const float* __restrict__ Wc1, const float* __restrict__ bc1,
                            const float* __restrict__ Wc2, const float* __restrict__ bc2,
                            float* __restrict__ out) {
    __shared__ float hs[2 * HID];
    int t = threadIdx.x;
    if (t < 2 * HID) {
        float s = 0.f;
        for (int r = 0; r < HS_ROWS; r++) s += hsumP[r * (2 * HID) + t];
        hs[t] = s;
    }
    __syncthreads();
    float val = 0.f;
    if (t < HID) {
        float acc = bc1[t];
        for (int i = 0; i < 2 * HID; i++) acc = fmaf(hs[i], Wc1[i * HID + t], acc);
        val = fmaxf(acc, 0.f) * Wc2[t];
    }
    for (int off = 32; off >= 1; off >>= 1) val += __shfl_xor(val, off, 64);
    if (t == 0) out[0] = 1.f / (1.f + expf(-(val + bc2[0])));
}

extern "C" void kernel_launch(void* const* d_in, const int* in_sizes, int n_in,
                              void* d_out, int out_size, void* d_ws, size_t ws_size,
                              hipStream_t stream) {
    const float* xg[2] = { (const float*)d_in[0], (const float*)d_in[2] };
    const int*   eg[2] = { (const int*)d_in[1],   (const int*)d_in[3] };
    const float* W1[3] = { (const float*)d_in[4], (const float*)d_in[8],  (const float*)d_in[12] };
    const float* b1[3] = { (const float*)d_in[5], (const float*)d_in[9],  (const float*)d_in[13] };
    const float* W2[3] = { (const float*)d_in[6], (const float*)d_in[10], (const float*)d_in[14] };
    const float* b2[3] = { (const float*)d_in[7], (const float*)d_in[11], (const float*)d_in[15] };
    const float* Wc1 = (const float*)d_in[16];
    const float* bc1 = (const float*)d_in[17];
    const float* Wc2 = (const float*)d_in[18];
    const float* bc2 = (const float*)d_in[19];

    const int N = in_sizes[0];
    const int E = in_sizes[1] / 2;

    // workspace layout (~33 MB)
    u8*       B0      = (u8*)d_ws;                        // N*32 bytes fp8 (3.2 MB)
    u8*       B1      = B0 + (size_t)N * 32;              // N*32 bytes fp8
    float*    hsumP   = (float*)(B1 + (size_t)N * 32);    // HS_ROWS * 2*HID partials
    int*      rowptr  = (int*)(hsumP + HS_ROWS * 2 * HID); // N+1
    int*      col     = rowptr + (N + 1);                 // E (25.6 MB)
    int*      cnt     = col + (size_t)E;                  // N
    int*      curp    = cnt + N;                          // N
    int*      bsum    = curp + N;                         // <=1024

    const int TB = 256;
    dim3 blk(TB);
    int gE4  = (E / 4 + TB - 1) / TB;        // hist/scatter: 4 edges/thread
    int nb   = (N + 1023) / 1024;            // scan blocks (98 for N=100000)
    int gN64 = (N + 63) / 64;                // mlp0: 4 lanes/node, 64 nodes/block
    int gN8  = (N + 31) / 32;                // mlp:  8 lanes/node, 32 nodes/block
    int gNz  = (N + TB - 1) / TB;

    zero_kernel<<<(HS_ROWS * 2 * HID + 255) / 256, 256, 0, stream>>>(hsumP, HS_ROWS * 2 * HID);

    for (int g = 0; g < 2; g++) {
        const float* x0  = xg[g];
        const int*   src = eg[g];
        const int*   dst = src + E;

        // ---- adjacency build (R12 direct CSR): hist -> 3-stage scan -> scatter ----
        zero_int<<<gNz, blk, 0, stream>>>(cnt, N);
        hist_edges<<<gE4, blk, 0, stream>>>(dst, cnt, E);
        scan_partial<<<nb, blk, 0, stream>>>(cnt, bsum, N);
        scan_blocksums<<<1, blk, 0, stream>>>(bsum, rowptr, nb, N);
        scan_write<<<nb, blk, 0, stream>>>(cnt, bsum, rowptr, curp, N);
        scatter_edges<<<gE4, blk, 0, stream>>>(src, dst, curp, col, E);

        // ---- layer 0 (d_in = 1), fp32 gather -> fp8 features ----
        mlp0_fused<<<gN64, blk, 0, stream>>>(rowptr, col, x0, W1[0], b1[0], W2[0], b2[0], B0, N);

        // ---- layer 1: fp8 gather+MLP  B0 -> B1 ----
        mlp_fused<false><<<gN8, blk, 0, stream>>>(rowptr, col, B0, W1[1], b1[1], W2[1], b2[1],
                                                  B1, nullptr, N);

        // ---- layer 2: fp8 gather+MLP + global add-pool ----
        mlp_fused<true><<<gN8, blk, 0, stream>>>(rowptr, col, B1, W1[2], b1[2], W2[2], b2[2],
                                                 nullptr, hsumP + g * HID, N);
    }

    head_kernel<<<1, 64, 0, stream>>>(hsumP, Wc1, bc1, Wc2, bc2, (float*)d_out);
}

// Round 13
// 573.018 us; speedup vs baseline: 2.9771x; 2.9771x over previous
//
#include <hip/hip_runtime.h>
#include <hip/hip_bf16.h>
#include <math.h>
#include <string.h>

#define HID 32
#define PSHIFT 8                 // dst bucket = dst >> 8 (256 nodes/bucket)
#define NPB (1 << PSHIFT)
#define MAXP 512                 // partition scan width (supports N <= 131072)
#define SLOTS 17408              // per-bucket staging; mean 16384, +8 sigma (guarded)
#define SBITS 3                  // src octile bits
#define SBINS (1 << SBITS)
#define NBINS (NPB * SBINS)      // 2048 counting-sort bins
#define GS 32                    // gcur stride in ints: 1 counter per 128B cacheline
#define HS_ROWS 32               // hsum partial rows (spread atomic contention)
#define COLBUF 3072              // mlp_fused col slice; 32 nodes, mean 2048 (guarded)
#define COLBUF0 6144             // mlp0 col slice; 64 nodes, mean 4096 (guarded)
typedef unsigned short u16;
typedef unsigned char u8;
typedef float f32x2 __attribute__((ext_vector_type(2)));

// ---------- fp8 e4m3 helpers (OCP; non-negative activations) ----------
__device__ inline float e42f_sw(unsigned b) {
    unsigned u = (b & 0x7fu) << 20;
    float f; memcpy(&f, &u, 4);
    return f * 0x1p120f;
}
__device__ inline unsigned f2e4_sw(float f) {
    f = fminf(f, 448.f);
    float y = f * 0x1p-120f;
    unsigned r; memcpy(&r, &y, 4);
    r = r + 0x7FFFFu + ((r >> 20) & 1u);
    return (r >> 20) & 0x7fu;
}
// accumulate 4 e4m3 (one u32) into a[0..3] — HW cvt when available (R9 win)
__device__ inline void acc_e4(float* a, unsigned w) {
#if __has_builtin(__builtin_amdgcn_cvt_pk_f32_fp8)
    f32x2 lo = __builtin_amdgcn_cvt_pk_f32_fp8(w, false);   // bytes 0,1
    f32x2 hi = __builtin_amdgcn_cvt_pk_f32_fp8(w, true);    // bytes 2,3
    a[0] += lo.x; a[1] += lo.y; a[2] += hi.x; a[3] += hi.y;
#else
    a[0] += e42f_sw(w);
    a[1] += e42f_sw(w >> 8);
    a[2] += e42f_sw(w >> 16);
    a[3] += e42f_sw(w >> 24);
#endif
}
__device__ inline unsigned pack_e4(float o0, float o1, float o2, float o3) {
#if __has_builtin(__builtin_amdgcn_cvt_pk_fp8_f32)
    unsigned pw = (unsigned)__builtin_amdgcn_cvt_pk_fp8_f32(
        fminf(o0, 448.f), fminf(o1, 448.f), 0, false);
    pw = (unsigned)__builtin_amdgcn_cvt_pk_fp8_f32(
        fminf(o2, 448.f), fminf(o3, 448.f), pw, true);
    return pw;
#else
    return f2e4_sw(o0) | (f2e4_sw(o1) << 8) | (f2e4_sw(o2) << 16) | (f2e4_sw(o3) << 24);
#endif
}

// ---------------- zero / init ----------------
__global__ void zero_kernel(float* __restrict__ p, int n) {
    int i = blockIdx.x * blockDim.x + threadIdx.x;
    if (i < n) p[i] = 0.f;
}
__global__ void init_gcur(int* __restrict__ gcur, int P) {
    int b = blockIdx.x * blockDim.x + threadIdx.x;
    if (b < P) gcur[b * GS] = b * SLOTS;
}

// ---------------- phase 1: partition (R7 version — proven fastest of 5 variants) ----
// R12 lesson: the staging pass exists to CONFINE each block's writes to a ~68KB
// bucket window (L2-resident) — direct scatter write-amplifies 15x (386MB, 530us).
__global__ void partition_edges(const int* __restrict__ src, const int* __restrict__ dst,
                                int* __restrict__ gcur, unsigned* __restrict__ staged,
                                int E, int P) {
    __shared__ int h[4][MAXP];
    __shared__ int hbase[MAXP];
    __shared__ int cur[MAXP];
    __shared__ int gbase[MAXP];
    __shared__ unsigned sortedv[4096];
    __shared__ u16 bktid[4096];
    __shared__ int wsums[4];
    __shared__ int sTotal;
    int t = threadIdx.x, wid = t >> 6, lane = t & 63;
    for (int i = t; i < 4 * MAXP; i += 256) (&h[0][0])[i] = 0;
    __syncthreads();

    int base = blockIdx.x * 4096;
    int4 S[4], D[4];
#pragma unroll
    for (int r = 0; r < 4; r++) {
        int e = base + r * 1024 + t * 4;
        if (e + 3 < E) {
            S[r] = *(const int4*)(src + e);
            D[r] = *(const int4*)(dst + e);
        } else {
            int s0[4], d0[4];
            for (int j = 0; j < 4; j++) {
                int ee = e + j;
                s0[j] = (ee < E) ? src[ee] : -1;
                d0[j] = (ee < E) ? dst[ee] : -1;
            }
            S[r] = make_int4(s0[0], s0[1], s0[2], s0[3]);
            D[r] = make_int4(d0[0], d0[1], d0[2], d0[3]);
        }
        if (D[r].x >= 0) atomicAdd(&h[wid][D[r].x >> PSHIFT], 1);
        if (D[r].y >= 0) atomicAdd(&h[wid][D[r].y >> PSHIFT], 1);
        if (D[r].z >= 0) atomicAdd(&h[wid][D[r].z >> PSHIFT], 1);
        if (D[r].w >= 0) atomicAdd(&h[wid][D[r].w >> PSHIFT], 1);
    }
    __syncthreads();

    int b0 = 2 * t, b1 = 2 * t + 1;
    int t0 = (b0 < P) ? (h[0][b0] + h[1][b0] + h[2][b0] + h[3][b0]) : 0;
    int t1 = (b1 < P) ? (h[0][b1] + h[1][b1] + h[2][b1] + h[3][b1]) : 0;
    int s = t0 + t1;
    int incl = s;
#pragma unroll
    for (int off = 1; off < 64; off <<= 1) {
        int u = __shfl_up(incl, off, 64);
        if (lane >= off) incl += u;
    }
    if (lane == 63) wsums[wid] = incl;
    __syncthreads();
    int woff = 0;
#pragma unroll
    for (int w = 0; w < 4; w++) if (w < wid) woff += wsums[w];
    int excl = woff + incl - s;
    if (b0 < P) { hbase[b0] = excl;      cur[b0] = excl; }
    if (b1 < P) { hbase[b1] = excl + t0; cur[b1] = excl + t0; }
    if (b0 < P && t0) gbase[b0] = atomicAdd(&gcur[b0 * GS], t0);
    if (b1 < P && t1) gbase[b1] = atomicAdd(&gcur[b1 * GS], t1);
    if (t == 255) sTotal = excl + s;
    __syncthreads();

#pragma unroll
    for (int r = 0; r < 4; r++) {
        int ss[4] = { S[r].x, S[r].y, S[r].z, S[r].w };
        int dd[4] = { D[r].x, D[r].y, D[r].z, D[r].w };
#pragma unroll
        for (int j = 0; j < 4; j++) {
            int d = dd[j];
            if (d >= 0) {
                int bk = d >> PSHIFT;
                int pos = atomicAdd(&cur[bk], 1);
                sortedv[pos] = ((unsigned)(d & (NPB - 1)) << 17) | (unsigned)ss[j];
                bktid[pos]   = (u16)bk;
            }
        }
    }
    __syncthreads();

    int total = sTotal;
    for (int i = t; i < total; i += 256) {
        int bk = bktid[i];
        int addr = gbase[bk] + (i - hbase[bk]);
        if (addr < (bk + 1) * SLOTS)
            staged[addr] = sortedv[i];
    }
}

// ---------------- phase 2: parallel scan over P bucket counts ----------------
__global__ void scan_buckets(const int* __restrict__ gcur, int* __restrict__ colbase,
                             int* __restrict__ rowptr, int P, int N) {
    __shared__ int wsums[4];
    int t = threadIdx.x, wid = t >> 6, lane = t & 63;
    int b0 = 2 * t, b1 = 2 * t + 1;
    int c0 = 0, c1 = 0;
    if (b0 < P) { c0 = gcur[b0 * GS] - b0 * SLOTS; if (c0 > SLOTS) c0 = SLOTS; }
    if (b1 < P) { c1 = gcur[b1 * GS] - b1 * SLOTS; if (c1 > SLOTS) c1 = SLOTS; }
    int s = c0 + c1;
    int incl = s;
#pragma unroll
    for (int off = 1; off < 64; off <<= 1) {
        int u = __shfl_up(incl, off, 64);
        if (lane >= off) incl += u;
    }
    if (lane == 63) wsums[wid] = incl;
    __syncthreads();
    int woff = 0;
#pragma unroll
    for (int w = 0; w < 4; w++) if (w < wid) woff += wsums[w];
    int excl = woff + incl - s;
    if (b0 < P) colbase[b0] = excl;
    if (b1 < P) colbase[b1] = excl + c0;
    if (t == 255) {
        colbase[P] = excl + s;
        rowptr[N]  = excl + s;
    }
}

// ---------------- phase 3: per-bucket counting sort ----------------
__global__ void sort_bucket(const unsigned* __restrict__ staged, const int* __restrict__ gcur,
                            const int* __restrict__ colbase,
                            int* __restrict__ rowptr, int* __restrict__ col, int N) {
    __shared__ int cnt[NBINS];
    __shared__ int wsum[4];
    __shared__ int sorted[SLOTS];
    int b = blockIdx.x;
    int t = threadIdx.x;
    int lane = t & 63, wid = t >> 6;
    int sBeg = b * SLOTS;
    int sEnd = gcur[b * GS]; if (sEnd > sBeg + SLOTS) sEnd = sBeg + SLOTS;
    int total = sEnd - sBeg;
    int colStart = colbase[b];
    int nodeBase = b << PSHIFT;

    for (int i = t; i < NBINS; i += 256) cnt[i] = 0;
    __syncthreads();
    for (int i = sBeg + t; i < sEnd; i += 256) {
        unsigned w = staged[i];
        int key = (int)((w >> 17) << SBITS) | (int)((w & 0x1FFFFu) >> 14);
        atomicAdd(&cnt[key], 1);
    }
    __syncthreads();

    int loc[SBINS]; int tot = 0;
#pragma unroll
    for (int k = 0; k < SBINS; k++) { loc[k] = tot; tot += cnt[(t << SBITS) + k]; }
    int incl = tot;
#pragma unroll
    for (int off = 1; off < 64; off <<= 1) {
        int u = __shfl_up(incl, off, 64);
        if (lane >= off) incl += u;
    }
    if (lane == 63) wsum[wid] = incl;
    __syncthreads();
    int woff = 0;
#pragma unroll
    for (int w = 0; w < 4; w++) if (w < wid) woff += wsum[w];
    int excl = woff + incl - tot;
    int node = nodeBase + t;
    if (node < N) rowptr[node] = colStart + excl;
#pragma unroll
    for (int k = 0; k < SBINS; k++) cnt[(t << SBITS) + k] = excl + loc[k];
    __syncthreads();

    for (int i = sBeg + t; i < sEnd; i += 256) {
        unsigned w = staged[i];
        int key = (int)((w >> 17) << SBITS) | (int)((w & 0x1FFFFu) >> 14);
        int pos = atomicAdd(&cnt[key], 1);
        sorted[pos] = (int)(w & 0x1FFFFu);
    }
    __syncthreads();
    for (int i = t; i < total; i += 256)
        col[colStart + i] = sorted[i];
}

// ---------------- layer 0 fused: gather(d=1) + MLP -> fp8 out ----------------
__global__ void mlp0_fused(const int* __restrict__ rowptr, const int* __restrict__ col,
                           const float* __restrict__ x0,
                           const float* __restrict__ W1, const float* __restrict__ b1,
                           const float* __restrict__ W2, const float* __restrict__ b2,
                           u8* __restrict__ out, int n) {
    __shared__ float sW1[HID], sb1[HID], sW2[HID * HID], sb2[HID];
    __shared__ int colbuf[COLBUF0];
    int t = threadIdx.x;
    if (t < HID) { sW1[t] = W1[t]; sb1[t] = b1[t]; sb2[t] = b2[t]; }
    for (int i = t; i < HID * HID; i += blockDim.x) sW2[i] = W2[i];

    int firstNode = blockIdx.x * 64;
    int lastNode  = firstNode + 64; if (lastNode > n) lastNode = n;
    int blockStart = (firstNode < n) ? rowptr[firstNode] : 0;
    int blockEnd   = (firstNode < n) ? rowptr[lastNode] : 0;
    int stagedCnt = blockEnd - blockStart; if (stagedCnt > COLBUF0) stagedCnt = COLBUF0;
    for (int i = t; i < stagedCnt; i += 256) colbuf[i] = col[blockStart + i];
    __syncthreads();

    int node = firstNode + (t >> 2);
    int q    = t & 3;
    int lane = t & 63;
    int base = lane & ~3;
    bool active = node < n;

    float s = 0.f;
    if (active) {
        int beg = rowptr[node], end = rowptr[node + 1];
        int jSplit = blockStart + stagedCnt; if (jSplit > end) jSplit = end;
        int j = beg + q;
        for (; j + 12 < jSplit; j += 16) {
            int c0 = colbuf[j - blockStart];
            int c1 = colbuf[j + 4 - blockStart];
            int c2 = colbuf[j + 8 - blockStart];
            int c3 = colbuf[j + 12 - blockStart];
            s += x0[c0]; s += x0[c1]; s += x0[c2]; s += x0[c3];
        }
        for (; j < jSplit; j += 4) s += x0[colbuf[j - blockStart]];
        for (; j < end; j += 4) s += x0[col[j]];
    }
    s += __shfl_xor(s, 1, 64);
    s += __shfl_xor(s, 2, 64);
    float v = active ? (x0[node] + s) : 0.f;

    float h[8];
#pragma unroll
    for (int i = 0; i < 8; i++) h[i] = fmaxf(fmaf(v, sW1[q * 8 + i], sb1[q * 8 + i]), 0.f);
    float o[8];
#pragma unroll
    for (int i = 0; i < 8; i++) o[i] = sb2[q * 8 + i];
#pragma unroll
    for (int k = 0; k < HID; k++) {
        float hk = __shfl(h[k & 7], base | (k >> 3), 64);
#pragma unroll
        for (int i = 0; i < 8; i++) o[i] = fmaf(hk, sW2[k * HID + q * 8 + i], o[i]);
    }
    if (active) {
        unsigned w0 = pack_e4(fmaxf(o[0], 0.f), fmaxf(o[1], 0.f),
                              fmaxf(o[2], 0.f), fmaxf(o[3], 0.f));
        unsigned w1 = pack_e4(fmaxf(o[4], 0.f), fmaxf(o[5], 0.f),
                              fmaxf(o[6], 0.f), fmaxf(o[7], 0.f));
        uint2 pk = make_uint2(w0, w1);
        *(uint2*)(out + ((size_t)node << 5) + (q << 3)) = pk;
    }
}

// ---------------- hidden layer fused: fp8 gather + MLP, 8 lanes/node, 32 nodes/block ----
// R13: gather loop unrolled 8->16 rows in flight (wave-level outstanding-load cap
// was the limiter per Little's-law analysis; VGPR stays < 64 so occupancy holds).
template <bool REDUCE>
__global__ void mlp_fused(const int* __restrict__ rowptr, const int* __restrict__ col,
                          const u8* __restrict__ xin,
                          const float* __restrict__ W1, const float* __restrict__ b1,
                          const float* __restrict__ W2, const float* __restrict__ b2,
                          u8* __restrict__ xout, float* __restrict__ hsum, int n) {
    __shared__ float sW1[HID * HID], sb1[HID], sW2[HID * HID], sb2[HID];
    __shared__ int colbuf[COLBUF];
    __shared__ float red[4][HID];
    int t = threadIdx.x;
    for (int i = t; i < HID * HID; i += blockDim.x) { sW1[i] = W1[i]; sW2[i] = W2[i]; }
    if (t < HID) { sb1[t] = b1[t]; sb2[t] = b2[t]; }

    int firstNode = blockIdx.x * 32;
    int lastNode  = firstNode + 32; if (lastNode > n) lastNode = n;
    int blockStart = (firstNode < n) ? rowptr[firstNode] : 0;
    int blockEnd   = (firstNode < n) ? rowptr[lastNode] : 0;
    int stagedCnt = blockEnd - blockStart; if (stagedCnt > COLBUF) stagedCnt = COLBUF;
    for (int i = t; i < stagedCnt; i += 256) colbuf[i] = col[blockStart + i];
    __syncthreads();

    int node = firstNode + (t >> 3);
    int q    = t & 7;            // lane owns features [q*4, q*4+4)
    int lane = t & 63;
    int base = lane & ~7;
    bool active = node < n;

    float va[4];
#pragma unroll
    for (int i = 0; i < 4; i++) va[i] = 0.f;
    if (active) {
        int beg = rowptr[node], end = rowptr[node + 1];
        const u8* xq = xin + (q << 2);
        float a0[4], a1[4], a2[4], a3[4];
#pragma unroll
        for (int i = 0; i < 4; i++) a0[i] = a1[i] = a2[i] = a3[i] = 0.f;
        {   // self term (eps = 0)
            unsigned w = *(const unsigned*)(xq + ((size_t)node << 5));
            acc_e4(a0, w);
        }
        int jSplit = blockStart + stagedCnt; if (jSplit > end) jSplit = end;
        int j = beg;
        for (; j + 16 <= jSplit; j += 16) {
            int lj = j - blockStart;
            int c0 = colbuf[lj+0],  c1 = colbuf[lj+1],  c2 = colbuf[lj+2],  c3 = colbuf[lj+3];
            int c4 = colbuf[lj+4],  c5 = colbuf[lj+5],  c6 = colbuf[lj+6],  c7 = colbuf[lj+7];
            int c8 = colbuf[lj+8],  c9 = colbuf[lj+9],  cA = colbuf[lj+10], cB = colbuf[lj+11];
            int cC = colbuf[lj+12], cD = colbuf[lj+13], cE = colbuf[lj+14], cF = colbuf[lj+15];
            unsigned w0 = *(const unsigned*)(xq + ((size_t)c0 << 5));
            unsigned w1 = *(const unsigned*)(xq + ((size_t)c1 << 5));
            unsigned w2 = *(const unsigned*)(xq + ((size_t)c2 << 5));
            unsigned w3 = *(const unsigned*)(xq + ((size_t)c3 << 5));
            unsigned w4 = *(const unsigned*)(xq + ((size_t)c4 << 5));
            unsigned w5 = *(const unsigned*)(xq + ((size_t)c5 << 5));
            unsigned w6 = *(const unsigned*)(xq + ((size_t)c6 << 5));
            unsigned w7 = *(const unsigned*)(xq + ((size_t)c7 << 5));
            unsigned w8 = *(const unsigned*)(xq + ((size_t)c8 << 5));
            unsigned w9 = *(const unsigned*)(xq + ((size_t)c9 << 5));
            unsigned wA = *(const unsigned*)(xq + ((size_t)cA << 5));
            unsigned wB = *(const unsigned*)(xq + ((size_t)cB << 5));
            unsigned wC = *(const unsigned*)(xq + ((size_t)cC << 5));
            unsigned wD = *(const unsigned*)(xq + ((size_t)cD << 5));
            unsigned wE = *(const unsigned*)(xq + ((size_t)cE << 5));
            unsigned wF = *(const unsigned*)(xq + ((size_t)cF << 5));
            acc_e4(a0, w0); acc_e4(a1, w1); acc_e4(a2, w2); acc_e4(a3, w3);
            acc_e4(a0, w4); acc_e4(a1, w5); acc_e4(a2, w6); acc_e4(a3, w7);
            acc_e4(a0, w8); acc_e4(a1, w9); acc_e4(a2, wA); acc_e4(a3, wB);
            acc_e4(a0, wC); acc_e4(a1, wD); acc_e4(a2, wE); acc_e4(a3, wF);
        }
        for (; j + 8 <= jSplit; j += 8) {
            int lj = j - blockStart;
            int c0 = colbuf[lj+0], c1 = colbuf[lj+1], c2 = colbuf[lj+2], c3 = colbuf[lj+3];
            int c4 = colbuf[lj+4], c5 = colbuf[lj+5], c6 = colbuf[lj+6], c7 = colbuf[lj+7];
            unsigned w0 = *(const unsigned*)(xq + ((size_t)c0 << 5));
            unsigned w1 = *(const unsigned*)(xq + ((size_t)c1 << 5));
            unsigned w2 = *(const unsigned*)(xq + ((size_t)c2 << 5));
            unsigned w3 = *(const unsigned*)(xq + ((size_t)c3 << 5));
            unsigned w4 = *(const unsigned*)(xq + ((size_t)c4 << 5));
            unsigned w5 = *(const unsigned*)(xq + ((size_t)c5 << 5));
            unsigned w6 = *(const unsigned*)(xq + ((size_t)c6 << 5));
            unsigned w7 = *(const unsigned*)(xq + ((size_t)c7 << 5));
            acc_e4(a0, w0); acc_e4(a1, w1); acc_e4(a2, w2); acc_e4(a3, w3);
            acc_e4(a0, w4); acc_e4(a1, w5); acc_e4(a2, w6); acc_e4(a3, w7);
        }
        for (; j < jSplit; j++) {
            unsigned w = *(const unsigned*)(xq + ((size_t)colbuf[j - blockStart] << 5));
            acc_e4(a0, w);
        }
        for (; j < end; j++) {   // colbuf overflow fallback (statistically unreachable)
            unsigned w = *(const unsigned*)(xq + ((size_t)col[j] << 5));
            acc_e4(a0, w);
        }
#pragma unroll
        for (int i = 0; i < 4; i++) va[i] = (a0[i] + a1[i]) + (a2[i] + a3[i]);
    }

    float h[4];
#pragma unroll
    for (int i = 0; i < 4; i++) h[i] = sb1[q * 4 + i];
#pragma unroll
    for (int k = 0; k < HID; k++) {
        float vk = __shfl(va[k & 3], base | (k >> 2), 64);
#pragma unroll
        for (int i = 0; i < 4; i++) h[i] = fmaf(vk, sW1[k * HID + q * 4 + i], h[i]);
    }
#pragma unroll
    for (int i = 0; i < 4; i++) h[i] = fmaxf(h[i], 0.f);

    float o[4];
#pragma unroll
    for (int i = 0; i < 4; i++) o[i] = sb2[q * 4 + i];
#pragma unroll
    for (int k = 0; k < HID; k++) {
        float hk = __shfl(h[k & 3], base | (k >> 2), 64);
#pragma unroll
        for (int i = 0; i < 4; i++) o[i] = fmaf(hk, sW2[k * HID + q * 4 + i], o[i]);
    }
#pragma unroll
    for (int i = 0; i < 4; i++) o[i] = fmaxf(o[i], 0.f);

    if (REDUCE) {
        if (!active) {
#pragma unroll
            for (int i = 0; i < 4; i++) o[i] = 0.f;
        }
#pragma unroll
        for (int i = 0; i < 4; i++) {   // sum the 8 nodes of this wave (lane bits 3..5)
            float v = o[i];
            v += __shfl_xor(v, 8, 64);
            v += __shfl_xor(v, 16, 64);
            v += __shfl_xor(v, 32, 64);
            o[i] = v;
        }
        int wid = t >> 6;
        if (lane < 8) {
#pragma unroll
            for (int i = 0; i < 4; i++) red[wid][lane * 4 + i] = o[i];
        }
        __syncthreads();
        if (t < HID) {
            float s = red[0][t] + red[1][t] + red[2][t] + red[3][t];
            atomicAdd(&hsum[(blockIdx.x & (HS_ROWS - 1)) * (2 * HID) + t], s);
        }
    } else if (active) {
        unsigned pw = pack_e4(o[0], o[1], o[2], o[3]);
        *(unsigned*)(xout + ((size_t)node << 5) + (q << 2)) = pw;
    }
}

// ---------------- head ----------------
__global__ void head_kernel(const float* __restrict__ hsumP,
                            const float* __restrict__ Wc1, const float* __restrict__ bc1,
                            const float* __restrict__ Wc2, const float* __restrict__ bc2,
                            float* __restrict__ out) {
    __shared__ float hs[2 * HID];
    int t = threadIdx.x;
    if (t < 2 * HID) {
        float s = 0.f;
        for (int r = 0; r < HS_ROWS; r++) s += hsumP[r * (2 * HID) + t];
        hs[t] = s;
    }
    __syncthreads();
    float val = 0.f;
    if (t < HID) {
        float acc = bc1[t];
        for (int i = 0; i < 2 * HID; i++) acc = fmaf(hs[i], Wc1[i * HID + t], acc);
        val = fmaxf(acc, 0.f) * Wc2[t];
    }
    for (int off = 32; off >= 1; off >>= 1) val += __shfl_xor(val, off, 64);
    if (t == 0) out[0] = 1.f / (1.f + expf(-(val + bc2[0])));
}

extern "C" void kernel_launch(void* const* d_in, const int* in_sizes, int n_in,
                              void* d_out, int out_size, void* d_ws, size_t ws_size,
                              hipStream_t stream) {
    const float* xg[2] = { (const float*)d_in[0], (const float*)d_in[2] };
    const int*   eg[2] = { (const int*)d_in[1],   (const int*)d_in[3] };
    const float* W1[3] = { (const float*)d_in[4], (const float*)d_in[8],  (const float*)d_in[12] };
    const float* b1[3] = { (const float*)d_in[5], (const float*)d_in[9],  (const float*)d_in[13] };
    const float* W2[3] = { (const float*)d_in[6], (const float*)d_in[10], (const float*)d_in[14] };
    const float* b2[3] = { (const float*)d_in[7], (const float*)d_in[11], (const float*)d_in[15] };
    const float* Wc1 = (const float*)d_in[16];
    const float* bc1 = (const float*)d_in[17];
    const float* Wc2 = (const float*)d_in[18];
    const float* bc2 = (const float*)d_in[19];

    const int N = in_sizes[0];
    const int E = in_sizes[1] / 2;
    const int P = (N + NPB - 1) >> PSHIFT;   // 391 for N=100000

    // workspace layout (~60 MB)
    u8*       B0      = (u8*)d_ws;                        // N*32 bytes fp8 (3.2 MB)
    u8*       B1      = B0 + (size_t)N * 32;              // N*32 bytes fp8
    float*    hsumP   = (float*)(B1 + (size_t)N * 32);    // HS_ROWS * 2*HID partials
    int*      rowptr  = (int*)(hsumP + HS_ROWS * 2 * HID); // N+1
    int*      col     = rowptr + (N + 1);                 // E
    int*      colbase = col + (size_t)E;                  // P+1
    int*      gcur    = colbase + (P + 1);                // P*GS (cacheline-padded)
    unsigned* staged  = (unsigned*)(gcur + (size_t)P * GS); // P*SLOTS (27.2 MB)

    const int TB = 256;
    dim3 blk(TB);
    int gE4k = (E + 4095) / 4096;            // 1563 partition blocks (R7 geometry)
    int gN64 = (N + 63) / 64;                // mlp0: 4 lanes/node, 64 nodes/block
    int gN8  = (N + 31) / 32;                // mlp:  8 lanes/node, 32 nodes/block
    int gP   = (P + TB - 1) / TB;

    zero_kernel<<<(HS_ROWS * 2 * HID + 255) / 256, 256, 0, stream>>>(hsumP, HS_ROWS * 2 * HID);

    for (int g = 0; g < 2; g++) {
        const float* x0  = xg[g];
        const int*   src = eg[g];
        const int*   dst = src + E;

        // ---- adjacency build: partition -> scan -> per-bucket sort ----
        init_gcur<<<gP, blk, 0, stream>>>(gcur, P);
        partition_edges<<<gE4k, blk, 0, stream>>>(src, dst, gcur, staged, E, P);
        scan_buckets<<<1, blk, 0, stream>>>(gcur, colbase, rowptr, P, N);
        sort_bucket<<<P, blk, 0, stream>>>(staged, gcur, colbase, rowptr, col, N);

        // ---- layer 0 (d_in = 1), fp32 gather -> fp8 features ----
        mlp0_fused<<<gN64, blk, 0, stream>>>(rowptr, col, x0, W1[0], b1[0], W2[0], b2[0], B0, N);

        // ---- layer 1: fp8 gather+MLP  B0 -> B1 ----
        mlp_fused<false><<<gN8, blk, 0, stream>>>(rowptr, col, B0, W1[1], b1[1], W2[1], b2[1],
                                                  B1, nullptr, N);

        // ---- layer 2: fp8 gather+MLP + global add-pool ----
        mlp_fused<true><<<gN8, blk, 0, stream>>>(rowptr, col, B1, W1[2], b1[2], W2[2], b2[2],
                                                 nullptr, hsumP + g * HID, N);
    }

    head_kernel<<<1, 64, 0, stream>>>(hsumP, Wc1, bc1, Wc2, bc2, (float*)d_out);
}

// Round 14
// 567.100 us; speedup vs baseline: 3.0081x; 1.0104x over previous
//
#include <hip/hip_runtime.h>
#include <hip/hip_bf16.h>
#include <math.h>
#include <string.h>

#define HID 32
#define PSHIFT 8                 // dst bucket = dst >> 8 (256 nodes/bucket)
#define NPB (1 << PSHIFT)
#define MAXP 512                 // partition scan width (supports N <= 131072)
#define SLOTS 17408              // per-bucket staging; mean 16384, +8 sigma (guarded)
#define GS 32                    // gcur stride in ints: 1 counter per 128B cacheline
#define HS_ROWS 32               // hsum partial rows (spread atomic contention)
#define COLBUF 3072              // mlp_fused col slice; 32 nodes, mean 2048 (guarded)
#define COLBUF0 6144             // mlp0 col slice; 64 nodes, mean 4096 (guarded)
typedef unsigned short u16;
typedef unsigned char u8;
typedef float f32x2 __attribute__((ext_vector_type(2)));

// ---------- fp8 e4m3 helpers (OCP; non-negative activations) ----------
__device__ inline float e42f_sw(unsigned b) {
    unsigned u = (b & 0x7fu) << 20;
    float f; memcpy(&f, &u, 4);
    return f * 0x1p120f;
}
__device__ inline unsigned f2e4_sw(float f) {
    f = fminf(f, 448.f);
    float y = f * 0x1p-120f;
    unsigned r; memcpy(&r, &y, 4);
    r = r + 0x7FFFFu + ((r >> 20) & 1u);
    return (r >> 20) & 0x7fu;
}
__device__ inline void acc_e4(float* a, unsigned w) {
#if __has_builtin(__builtin_amdgcn_cvt_pk_f32_fp8)
    f32x2 lo = __builtin_amdgcn_cvt_pk_f32_fp8(w, false);
    f32x2 hi = __builtin_amdgcn_cvt_pk_f32_fp8(w, true);
    a[0] += lo.x; a[1] += lo.y; a[2] += hi.x; a[3] += hi.y;
#else
    a[0] += e42f_sw(w);
    a[1] += e42f_sw(w >> 8);
    a[2] += e42f_sw(w >> 16);
    a[3] += e42f_sw(w >> 24);
#endif
}
__device__ inline unsigned pack_e4(float o0, float o1, float o2, float o3) {
#if __has_builtin(__builtin_amdgcn_cvt_pk_fp8_f32)
    unsigned pw = (unsigned)__builtin_amdgcn_cvt_pk_fp8_f32(
        fminf(o0, 448.f), fminf(o1, 448.f), 0, false);
    pw = (unsigned)__builtin_amdgcn_cvt_pk_fp8_f32(
        fminf(o2, 448.f), fminf(o3, 448.f), pw, true);
    return pw;
#else
    return f2e4_sw(o0) | (f2e4_sw(o1) << 8) | (f2e4_sw(o2) << 16) | (f2e4_sw(o3) << 24);
#endif
}

// ---------------- zero / init ----------------
__global__ void zero_kernel(float* __restrict__ p, int n) {
    int i = blockIdx.x * blockDim.x + threadIdx.x;
    if (i < n) p[i] = 0.f;
}
// init both graphs' gcur (gB may equal gA in sequential mode; idempotent)
__global__ void init_gcur2(int* __restrict__ gA, int* __restrict__ gB, int P) {
    int i = blockIdx.x * blockDim.x + threadIdx.x;
    if (i < P) gA[i * GS] = i * SLOTS;
    else if (i < 2 * P) { int b = i - P; gB[b * GS] = b * SLOTS; }
}

// ---------------- phase 1: partition (R7 core, graph-batched grid) ----------------
// R12 lesson: staging confines writes to ~68KB bucket windows (L2-resident).
__global__ void partition_edges(const int* __restrict__ srcA, const int* __restrict__ dstA,
                                int* __restrict__ gcurA, unsigned* __restrict__ stagedA,
                                const int* __restrict__ srcB, const int* __restrict__ dstB,
                                int* __restrict__ gcurB, unsigned* __restrict__ stagedB,
                                int gsplit, int E, int P) {
    __shared__ int h[4][MAXP];
    __shared__ int hbase[MAXP];
    __shared__ int cur[MAXP];
    __shared__ int gbase[MAXP];
    __shared__ unsigned sortedv[4096];
    __shared__ u16 bktid[4096];
    __shared__ int wsums[4];
    __shared__ int sTotal;
    const int* src; const int* dst; int* gcur; unsigned* staged;
    int bid = blockIdx.x;
    if (bid < gsplit) { src = srcA; dst = dstA; gcur = gcurA; staged = stagedA; }
    else { bid -= gsplit; src = srcB; dst = dstB; gcur = gcurB; staged = stagedB; }

    int t = threadIdx.x, wid = t >> 6, lane = t & 63;
    for (int i = t; i < 4 * MAXP; i += 256) (&h[0][0])[i] = 0;
    __syncthreads();

    int base = bid * 4096;
    int4 S[4], D[4];
#pragma unroll
    for (int r = 0; r < 4; r++) {
        int e = base + r * 1024 + t * 4;
        if (e + 3 < E) {
            S[r] = *(const int4*)(src + e);
            D[r] = *(const int4*)(dst + e);
        } else {
            int s0[4], d0[4];
            for (int j = 0; j < 4; j++) {
                int ee = e + j;
                s0[j] = (ee < E) ? src[ee] : -1;
                d0[j] = (ee < E) ? dst[ee] : -1;
            }
            S[r] = make_int4(s0[0], s0[1], s0[2], s0[3]);
            D[r] = make_int4(d0[0], d0[1], d0[2], d0[3]);
        }
        if (D[r].x >= 0) atomicAdd(&h[wid][D[r].x >> PSHIFT], 1);
        if (D[r].y >= 0) atomicAdd(&h[wid][D[r].y >> PSHIFT], 1);
        if (D[r].z >= 0) atomicAdd(&h[wid][D[r].z >> PSHIFT], 1);
        if (D[r].w >= 0) atomicAdd(&h[wid][D[r].w >> PSHIFT], 1);
    }
    __syncthreads();

    int b0 = 2 * t, b1 = 2 * t + 1;
    int t0 = (b0 < P) ? (h[0][b0] + h[1][b0] + h[2][b0] + h[3][b0]) : 0;
    int t1 = (b1 < P) ? (h[0][b1] + h[1][b1] + h[2][b1] + h[3][b1]) : 0;
    int s = t0 + t1;
    int incl = s;
#pragma unroll
    for (int off = 1; off < 64; off <<= 1) {
        int u = __shfl_up(incl, off, 64);
        if (lane >= off) incl += u;
    }
    if (lane == 63) wsums[wid] = incl;
    __syncthreads();
    int woff = 0;
#pragma unroll
    for (int w = 0; w < 4; w++) if (w < wid) woff += wsums[w];
    int excl = woff + incl - s;
    if (b0 < P) { hbase[b0] = excl;      cur[b0] = excl; }
    if (b1 < P) { hbase[b1] = excl + t0; cur[b1] = excl + t0; }
    if (b0 < P && t0) gbase[b0] = atomicAdd(&gcur[b0 * GS], t0);
    if (b1 < P && t1) gbase[b1] = atomicAdd(&gcur[b1 * GS], t1);
    if (t == 255) sTotal = excl + s;
    __syncthreads();

#pragma unroll
    for (int r = 0; r < 4; r++) {
        int ss[4] = { S[r].x, S[r].y, S[r].z, S[r].w };
        int dd[4] = { D[r].x, D[r].y, D[r].z, D[r].w };
#pragma unroll
        for (int j = 0; j < 4; j++) {
            int d = dd[j];
            if (d >= 0) {
                int bk = d >> PSHIFT;
                int pos = atomicAdd(&cur[bk], 1);
                sortedv[pos] = ((unsigned)(d & (NPB - 1)) << 17) | (unsigned)ss[j];
                bktid[pos]   = (u16)bk;
            }
        }
    }
    __syncthreads();

    int total = sTotal;
    for (int i = t; i < total; i += 256) {
        int bk = bktid[i];
        int addr = gbase[bk] + (i - hbase[bk]);
        if (addr < (bk + 1) * SLOTS)
            staged[addr] = sortedv[i];
    }
}

// ---------------- phase 2: bucket-count scan; block per graph ----------------
__global__ void scan_buckets(const int* __restrict__ gcurA, int* __restrict__ colbaseA,
                             int* __restrict__ rowptrA,
                             const int* __restrict__ gcurB, int* __restrict__ colbaseB,
                             int* __restrict__ rowptrB, int P, int N) {
    __shared__ int wsums[4];
    const int* gcur; int* colbase; int* rowptr;
    if (blockIdx.x == 0) { gcur = gcurA; colbase = colbaseA; rowptr = rowptrA; }
    else { gcur = gcurB; colbase = colbaseB; rowptr = rowptrB; }
    int t = threadIdx.x, wid = t >> 6, lane = t & 63;
    int b0 = 2 * t, b1 = 2 * t + 1;
    int c0 = 0, c1 = 0;
    if (b0 < P) { c0 = gcur[b0 * GS] - b0 * SLOTS; if (c0 > SLOTS) c0 = SLOTS; }
    if (b1 < P) { c1 = gcur[b1 * GS] - b1 * SLOTS; if (c1 > SLOTS) c1 = SLOTS; }
    int s = c0 + c1;
    int incl = s;
#pragma unroll
    for (int off = 1; off < 64; off <<= 1) {
        int u = __shfl_up(incl, off, 64);
        if (lane >= off) incl += u;
    }
    if (lane == 63) wsums[wid] = incl;
    __syncthreads();
    int woff = 0;
#pragma unroll
    for (int w = 0; w < 4; w++) if (w < wid) woff += wsums[w];
    int excl = woff + incl - s;
    if (b0 < P) colbase[b0] = excl;
    if (b1 < P) colbase[b1] = excl + c0;
    if (t == 255) {
        colbase[P] = excl + s;
        rowptr[N]  = excl + s;
    }
}

// ---------------- phase 3: per-bucket counting "sort" -> direct global col -------
// R14: key = dst_local only (fp8 L2-resident since R7 -> octile locality dead);
// writes go straight to col's 64KB bucket window (single-block-owned, L2-local).
// LDS 78KB -> ~1KB.
__global__ void sort_bucket(const unsigned* __restrict__ stagedA, const int* __restrict__ gcurA,
                            const int* __restrict__ colbaseA, int* __restrict__ rowptrA,
                            int* __restrict__ colA,
                            const unsigned* __restrict__ stagedB, const int* __restrict__ gcurB,
                            const int* __restrict__ colbaseB, int* __restrict__ rowptrB,
                            int* __restrict__ colB,
                            int gsplit, int N) {
    __shared__ int cnt[NPB];
    __shared__ int wsum[4];
    const unsigned* staged; const int* gcur; const int* colbase; int* rowptr; int* col;
    int b = blockIdx.x;
    if (b < gsplit) { staged = stagedA; gcur = gcurA; colbase = colbaseA; rowptr = rowptrA; col = colA; }
    else { b -= gsplit; staged = stagedB; gcur = gcurB; colbase = colbaseB; rowptr = rowptrB; col = colB; }
    int t = threadIdx.x, lane = t & 63, wid = t >> 6;
    int sBeg = b * SLOTS;
    int sEnd = gcur[b * GS]; if (sEnd > sBeg + SLOTS) sEnd = sBeg + SLOTS;
    int colStart = colbase[b];
    int nodeBase = b << PSHIFT;

    cnt[t] = 0;                          // NPB == 256 == blockDim
    __syncthreads();
    for (int i = sBeg + t; i < sEnd; i += 256)
        atomicAdd(&cnt[staged[i] >> 17], 1);
    __syncthreads();

    int myc = cnt[t];
    int incl = myc;
#pragma unroll
    for (int off = 1; off < 64; off <<= 1) {
        int u = __shfl_up(incl, off, 64);
        if (lane >= off) incl += u;
    }
    if (lane == 63) wsum[wid] = incl;
    __syncthreads();
    int woff = 0;
#pragma unroll
    for (int w = 0; w < 4; w++) if (w < wid) woff += wsum[w];
    int excl = woff + incl - myc;
    int node = nodeBase + t;
    if (node < N) rowptr[node] = colStart + excl;
    __syncthreads();
    cnt[t] = colStart + excl;            // global col cursor for node t
    __syncthreads();

    for (int i = sBeg + t; i < sEnd; i += 256) {
        unsigned w = staged[i];
        int pos = atomicAdd(&cnt[w >> 17], 1);
        col[pos] = (int)(w & 0x1FFFFu);
    }
}

// ---------------- layer 0 fused: gather(d=1) + MLP -> fp8 out (graph-batched) -----
__global__ void mlp0_fused(const int* __restrict__ rowptrA, const int* __restrict__ colA,
                           const float* __restrict__ x0A, u8* __restrict__ outA,
                           const int* __restrict__ rowptrB, const int* __restrict__ colB,
                           const float* __restrict__ x0B, u8* __restrict__ outB,
                           const float* __restrict__ W1, const float* __restrict__ b1,
                           const float* __restrict__ W2, const float* __restrict__ b2,
                           int gsplit, int n) {
    __shared__ float sW1[HID], sb1[HID], sW2[HID * HID], sb2[HID];
    __shared__ int colbuf[COLBUF0];
    const int* rowptr; const int* col; const float* x0; u8* out;
    int bid = blockIdx.x;
    if (bid < gsplit) { rowptr = rowptrA; col = colA; x0 = x0A; out = outA; }
    else { bid -= gsplit; rowptr = rowptrB; col = colB; x0 = x0B; out = outB; }
    int t = threadIdx.x;
    if (t < HID) { sW1[t] = W1[t]; sb1[t] = b1[t]; sb2[t] = b2[t]; }
    for (int i = t; i < HID * HID; i += blockDim.x) sW2[i] = W2[i];

    int firstNode = bid * 64;
    int lastNode  = firstNode + 64; if (lastNode > n) lastNode = n;
    int blockStart = (firstNode < n) ? rowptr[firstNode] : 0;
    int blockEnd   = (firstNode < n) ? rowptr[lastNode] : 0;
    int stagedCnt = blockEnd - blockStart; if (stagedCnt > COLBUF0) stagedCnt = COLBUF0;
    for (int i = t; i < stagedCnt; i += 256) colbuf[i] = col[blockStart + i];
    __syncthreads();

    int node = firstNode + (t >> 2);
    int q    = t & 3;
    int lane = t & 63;
    int base = lane & ~3;
    bool active = node < n;

    float s = 0.f;
    if (active) {
        int beg = rowptr[node], end = rowptr[node + 1];
        int jSplit = blockStart + stagedCnt; if (jSplit > end) jSplit = end;
        int j = beg + q;
        for (; j + 12 < jSplit; j += 16) {
            int c0 = colbuf[j - blockStart];
            int c1 = colbuf[j + 4 - blockStart];
            int c2 = colbuf[j + 8 - blockStart];
            int c3 = colbuf[j + 12 - blockStart];
            s += x0[c0]; s += x0[c1]; s += x0[c2]; s += x0[c3];
        }
        for (; j < jSplit; j += 4) s += x0[colbuf[j - blockStart]];
        for (; j < end; j += 4) s += x0[col[j]];
    }
    s += __shfl_xor(s, 1, 64);
    s += __shfl_xor(s, 2, 64);
    float v = active ? (x0[node] + s) : 0.f;

    float h[8];
#pragma unroll
    for (int i = 0; i < 8; i++) h[i] = fmaxf(fmaf(v, sW1[q * 8 + i], sb1[q * 8 + i]), 0.f);
    float o[8];
#pragma unroll
    for (int i = 0; i < 8; i++) o[i] = sb2[q * 8 + i];
#pragma unroll
    for (int k = 0; k < HID; k++) {
        float hk = __shfl(h[k & 7], base | (k >> 3), 64);
#pragma unroll
        for (int i = 0; i < 8; i++) o[i] = fmaf(hk, sW2[k * HID + q * 8 + i], o[i]);
    }
    if (active) {
        unsigned w0 = pack_e4(fmaxf(o[0], 0.f), fmaxf(o[1], 0.f),
                              fmaxf(o[2], 0.f), fmaxf(o[3], 0.f));
        unsigned w1 = pack_e4(fmaxf(o[4], 0.f), fmaxf(o[5], 0.f),
                              fmaxf(o[6], 0.f), fmaxf(o[7], 0.f));
        uint2 pk = make_uint2(w0, w1);
        *(uint2*)(out + ((size_t)node << 5) + (q << 3)) = pk;
    }
}

// ---------------- hidden layer fused: fp8 gather + MLP (graph-batched) ----------
// R9 8-wide gather (R13 16-wide was null: per-CU MSHR cap, not per-wave).
template <bool REDUCE>
__global__ void mlp_fused(const int* __restrict__ rowptrA, const int* __restrict__ colA,
                          const u8* __restrict__ xinA, u8* __restrict__ xoutA,
                          float* __restrict__ hsumA,
                          const int* __restrict__ rowptrB, const int* __restrict__ colB,
                          const u8* __restrict__ xinB, u8* __restrict__ xoutB,
                          float* __restrict__ hsumB,
                          const float* __restrict__ W1, const float* __restrict__ b1,
                          const float* __restrict__ W2, const float* __restrict__ b2,
                          int gsplit, int n) {
    __shared__ float sW1[HID * HID], sb1[HID], sW2[HID * HID], sb2[HID];
    __shared__ int colbuf[COLBUF];
    __shared__ float red[4][HID];
    const int* rowptr; const int* col; const u8* xin; u8* xout; float* hsum;
    int bid = blockIdx.x;
    if (bid < gsplit) { rowptr = rowptrA; col = colA; xin = xinA; xout = xoutA; hsum = hsumA; }
    else { bid -= gsplit; rowptr = rowptrB; col = colB; xin = xinB; xout = xoutB; hsum = hsumB; }
    int t = threadIdx.x;
    for (int i = t; i < HID * HID; i += blockDim.x) { sW1[i] = W1[i]; sW2[i] = W2[i]; }
    if (t < HID) { sb1[t] = b1[t]; sb2[t] = b2[t]; }

    int firstNode = bid * 32;
    int lastNode  = firstNode + 32; if (lastNode > n) lastNode = n;
    int blockStart = (firstNode < n) ? rowptr[firstNode] : 0;
    int blockEnd   = (firstNode < n) ? rowptr[lastNode] : 0;
    int stagedCnt = blockEnd - blockStart; if (stagedCnt > COLBUF) stagedCnt = COLBUF;
    for (int i = t; i < stagedCnt; i += 256) colbuf[i] = col[blockStart + i];
    __syncthreads();

    int node = firstNode + (t >> 3);
    int q    = t & 7;
    int lane = t & 63;
    int base = lane & ~7;
    bool active = node < n;

    float va[4];
#pragma unroll
    for (int i = 0; i < 4; i++) va[i] = 0.f;
    if (active) {
        int beg = rowptr[node], end = rowptr[node + 1];
        const u8* xq = xin + (q << 2);
        float a0[4], a1[4], a2[4], a3[4];
#pragma unroll
        for (int i = 0; i < 4; i++) a0[i] = a1[i] = a2[i] = a3[i] = 0.f;
        {   // self term (eps = 0)
            unsigned w = *(const unsigned*)(xq + ((size_t)node << 5));
            acc_e4(a0, w);
        }
        int jSplit = blockStart + stagedCnt; if (jSplit > end) jSplit = end;
        int j = beg;
        for (; j + 8 <= jSplit; j += 8) {
            int lj = j - blockStart;
            int c0 = colbuf[lj+0], c1 = colbuf[lj+1], c2 = colbuf[lj+2], c3 = colbuf[lj+3];
            int c4 = colbuf[lj+4], c5 = colbuf[lj+5], c6 = colbuf[lj+6], c7 = colbuf[lj+7];
            unsigned w0 = *(const unsigned*)(xq + ((size_t)c0 << 5));
            unsigned w1 = *(const unsigned*)(xq + ((size_t)c1 << 5));
            unsigned w2 = *(const unsigned*)(xq + ((size_t)c2 << 5));
            unsigned w3 = *(const unsigned*)(xq + ((size_t)c3 << 5));
            unsigned w4 = *(const unsigned*)(xq + ((size_t)c4 << 5));
            unsigned w5 = *(const unsigned*)(xq + ((size_t)c5 << 5));
            unsigned w6 = *(const unsigned*)(xq + ((size_t)c6 << 5));
            unsigned w7 = *(const unsigned*)(xq + ((size_t)c7 << 5));
            acc_e4(a0, w0); acc_e4(a1, w1); acc_e4(a2, w2); acc_e4(a3, w3);
            acc_e4(a0, w4); acc_e4(a1, w5); acc_e4(a2, w6); acc_e4(a3, w7);
        }
        for (; j < jSplit; j++) {
            unsigned w = *(const unsigned*)(xq + ((size_t)colbuf[j - blockStart] << 5));
            acc_e4(a0, w);
        }
        for (; j < end; j++) {
            unsigned w = *(const unsigned*)(xq + ((size_t)col[j] << 5));
            acc_e4(a0, w);
        }
#pragma unroll
        for (int i = 0; i < 4; i++) va[i] = (a0[i] + a1[i]) + (a2[i] + a3[i]);
    }

    float h[4];
#pragma unroll
    for (int i = 0; i < 4; i++) h[i] = sb1[q * 4 + i];
#pragma unroll
    for (int k = 0; k < HID; k++) {
        float vk = __shfl(va[k & 3], base | (k >> 2), 64);
#pragma unroll
        for (int i = 0; i < 4; i++) h[i] = fmaf(vk, sW1[k * HID + q * 4 + i], h[i]);
    }
#pragma unroll
    for (int i = 0; i < 4; i++) h[i] = fmaxf(h[i], 0.f);

    float o[4];
#pragma unroll
    for (int i = 0; i < 4; i++) o[i] = sb2[q * 4 + i];
#pragma unroll
    for (int k = 0; k < HID; k++) {
        float hk = __shfl(h[k & 3], base | (k >> 2), 64);
#pragma unroll
        for (int i = 0; i < 4; i++) o[i] = fmaf(hk, sW2[k * HID + q * 4 + i], o[i]);
    }
#pragma unroll
    for (int i = 0; i < 4; i++) o[i] = fmaxf(o[i], 0.f);

    if (REDUCE) {
        if (!active) {
#pragma unroll
            for (int i = 0; i < 4; i++) o[i] = 0.f;
        }
#pragma unroll
        for (int i = 0; i < 4; i++) {
            float v = o[i];
            v += __shfl_xor(v, 8, 64);
            v += __shfl_xor(v, 16, 64);
            v += __shfl_xor(v, 32, 64);
            o[i] = v;
        }
        int wid = t >> 6;
        if (lane < 8) {
#pragma unroll
            for (int i = 0; i < 4; i++) red[wid][lane * 4 + i] = o[i];
        }
        __syncthreads();
        if (t < HID) {
            float s = red[0][t] + red[1][t] + red[2][t] + red[3][t];
            atomicAdd(&hsum[(blockIdx.x & (HS_ROWS - 1)) * (2 * HID) + t], s);
        }
    } else if (active) {
        unsigned pw = pack_e4(o[0], o[1], o[2], o[3]);
        *(unsigned*)(xout + ((size_t)node << 5) + (q << 2)) = pw;
    }
}

// ---------------- head ----------------
__global__ void head_kernel(const float* __restrict__ hsumP,
                            const float* __restrict__ Wc1, const float* __restrict__ bc1,
                            const float* __restrict__ Wc2, const float* __restrict__ bc2,
                            float* __restrict__ out) {
    __shared__ float hs[2 * HID];
    int t = threadIdx.x;
    if (t < 2 * HID) {
        float s = 0.f;
        for (int r = 0; r < HS_ROWS; r++) s += hsumP[r * (2 * HID) + t];
        hs[t] = s;
    }
    __syncthreads();
    float val = 0.f;
    if (t < HID) {
        float acc = bc1[t];
        for (int i = 0; i < 2 * HID; i++) acc = fmaf(hs[i], Wc1[i * HID + t], acc);
        val = fmaxf(acc, 0.f) * Wc2[t];
    }
    for (int off = 32; off >= 1; off >>= 1) val += __shfl_xor(val, off, 64);
    if (t == 0) out[0] = 1.f / (1.f + expf(-(val + bc2[0])));
}

extern "C" void kernel_launch(void* const* d_in, const int* in_sizes, int n_in,
                              void* d_out, int out_size, void* d_ws, size_t ws_size,
                              hipStream_t stream) {
    const float* xg[2] = { (const float*)d_in[0], (const float*)d_in[2] };
    const int*   eg[2] = { (const int*)d_in[1],   (const int*)d_in[3] };
    const float* W1[3] = { (const float*)d_in[4], (const float*)d_in[8],  (const float*)d_in[12] };
    const float* b1[3] = { (const float*)d_in[5], (const float*)d_in[9],  (const float*)d_in[13] };
    const float* W2[3] = { (const float*)d_in[6], (const float*)d_in[10], (const float*)d_in[14] };
    const float* b2[3] = { (const float*)d_in[7], (const float*)d_in[11], (const float*)d_in[15] };
    const float* Wc1 = (const float*)d_in[16];
    const float* bc1 = (const float*)d_in[17];
    const float* Wc2 = (const float*)d_in[18];
    const float* bc2 = (const float*)d_in[19];

    const int N = in_sizes[0];
    const int E = in_sizes[1] / 2;
    const int P = (N + NPB - 1) >> PSHIFT;   // 391 for N=100000

    const int TB = 256;
    dim3 blk(TB);
    int gE4k = (E + 4095) / 4096;
    int gN64 = (N + 63) / 64;
    int gN8  = (N + 31) / 32;

    // per-graph sizes (bytes)
    size_t szB    = (size_t)N * 32;                    // fp8 feature table
    size_t szRow  = (size_t)(N + 1) * 4;
    size_t szCol  = (size_t)E * 4;
    size_t szCb   = (size_t)(P + 1) * 4;
    size_t szGcur = (size_t)P * GS * 4;
    size_t szStg  = (size_t)P * SLOTS * 4;
    size_t szHsum = (size_t)HS_ROWS * 2 * HID * 4;
    size_t needBatched = 4 * szB + szHsum + 2 * (szRow + szCol + szCb + szGcur + szStg) + 1024;

    char* w = (char*)d_ws;
    auto take = [&](size_t sz) { char* p = w; w += (sz + 255) & ~(size_t)255; return p; };

    if (ws_size >= needBatched) {
        // ================= batched path: both graphs per dispatch =================
        u8*    B0[2]  = { (u8*)take(szB), (u8*)take(szB) };
        u8*    B1[2]  = { (u8*)take(szB), (u8*)take(szB) };
        float* hsumP  = (float*)take(szHsum);
        int*   rowp[2] = { (int*)take(szRow), (int*)take(szRow) };
        int*   col[2]  = { (int*)take(szCol), (int*)take(szCol) };
        int*   cb[2]   = { (int*)take(szCb), (int*)take(szCb) };
        int*   gc[2]   = { (int*)take(szGcur), (int*)take(szGcur) };
        unsigned* st[2] = { (unsigned*)take(szStg), (unsigned*)take(szStg) };

        zero_kernel<<<(HS_ROWS * 2 * HID + 255) / 256, 256, 0, stream>>>(hsumP, HS_ROWS * 2 * HID);
        init_gcur2<<<(2 * P + TB - 1) / TB, blk, 0, stream>>>(gc[0], gc[1], P);
        partition_edges<<<2 * gE4k, blk, 0, stream>>>(eg[0], eg[0] + E, gc[0], st[0],
                                                      eg[1], eg[1] + E, gc[1], st[1],
                                                      gE4k, E, P);
        scan_buckets<<<2, blk, 0, stream>>>(gc[0], cb[0], rowp[0], gc[1], cb[1], rowp[1], P, N);
        sort_bucket<<<2 * P, blk, 0, stream>>>(st[0], gc[0], cb[0], rowp[0], col[0],
                                               st[1], gc[1], cb[1], rowp[1], col[1], P, N);
        mlp0_fused<<<2 * gN64, blk, 0, stream>>>(rowp[0], col[0], xg[0], B0[0],
                                                 rowp[1], col[1], xg[1], B0[1],
                                                 W1[0], b1[0], W2[0], b2[0], gN64, N);
        mlp_fused<false><<<2 * gN8, blk, 0, stream>>>(rowp[0], col[0], B0[0], B1[0], nullptr,
                                                      rowp[1], col[1], B0[1], B1[1], nullptr,
                                                      W1[1], b1[1], W2[1], b2[1], gN8, N);
        mlp_fused<true><<<2 * gN8, blk, 0, stream>>>(rowp[0], col[0], B1[0], nullptr, hsumP,
                                                     rowp[1], col[1], B1[1], nullptr, hsumP + HID,
                                                     W1[2], b1[2], W2[2], b2[2], gN8, N);
        head_kernel<<<1, 64, 0, stream>>>(hsumP, Wc1, bc1, Wc2, bc2, (float*)d_out);
    } else {
        // ================= sequential fallback (R9 flow) =================
        u8*    B0s    = (u8*)take(szB);
        u8*    B1s    = (u8*)take(szB);
        float* hsumP  = (float*)take(szHsum);
        int*   rowp   = (int*)take(szRow);
        int*   colp   = (int*)take(szCol);
        int*   cbp    = (int*)take(szCb);
        int*   gcp    = (int*)take(szGcur);
        unsigned* stp = (unsigned*)take(szStg);

        zero_kernel<<<(HS_ROWS * 2 * HID + 255) / 256, 256, 0, stream>>>(hsumP, HS_ROWS * 2 * HID);
        for (int g = 0; g < 2; g++) {
            const float* x0  = xg[g];
            const int*   src = eg[g];
            const int*   dst = src + E;
            init_gcur2<<<(P + TB - 1) / TB, blk, 0, stream>>>(gcp, gcp, P);
            partition_edges<<<gE4k, blk, 0, stream>>>(src, dst, gcp, stp,
                                                      src, dst, gcp, stp, gE4k, E, P);
            scan_buckets<<<1, blk, 0, stream>>>(gcp, cbp, rowp, gcp, cbp, rowp, P, N);
            sort_bucket<<<P, blk, 0, stream>>>(stp, gcp, cbp, rowp, colp,
                                               stp, gcp, cbp, rowp, colp, P, N);
            mlp0_fused<<<gN64, blk, 0, stream>>>(rowp, colp, x0, B0s,
                                                 rowp, colp, x0, B0s,
                                                 W1[0], b1[0], W2[0], b2[0], gN64, N);
            mlp_fused<false><<<gN8, blk, 0, stream>>>(rowp, colp, B0s, B1s, nullptr,
                                                      rowp, colp, B0s, B1s, nullptr,
                                                      W1[1], b1[1], W2[1], b2[1], gN8, N);
            mlp_fused<true><<<gN8, blk, 0, stream>>>(rowp, colp, B1s, nullptr, hsumP + g * HID,
                                                     rowp, colp, B1s, nullptr, hsumP + g * HID,
                                                     W1[2], b1[2], W2[2], b2[2], gN8, N);
        }
        head_kernel<<<1, 64, 0, stream>>>(hsumP, Wc1, bc1, Wc2, bc2, (float*)d_out);
    }
}

// Round 15
// 526.598 us; speedup vs baseline: 3.2395x; 1.0769x over previous
//
#include <hip/hip_runtime.h>
#include <hip/hip_bf16.h>
#include <math.h>
#include <string.h>

#define HID 32
#define PSHIFT 8                 // dst bucket = dst >> 8 (256 nodes/bucket)
#define NPB (1 << PSHIFT)
#define MAXP 512                 // partition scan width (supports N <= 131072)
#define SLOTS 17408              // per-bucket staging; mean 16384, +8 sigma (guarded)
#define GS 32                    // gcur stride in ints: 1 counter per 128B cacheline
#define HS_ROWS 32               // hsum partial rows (spread atomic contention)
#define COLBUF 3072              // mlp_fused col slice; 32 nodes, mean 2048 (guarded)
#define COLBUF0 6144             // mlp0 col slice; 64 nodes, mean 4096 (guarded)
typedef unsigned short u16;
typedef unsigned char u8;
typedef float f32x2 __attribute__((ext_vector_type(2)));

// ---------- fp8 e4m3 helpers (OCP; non-negative activations) ----------
__device__ inline float e42f_sw(unsigned b) {
    unsigned u = (b & 0x7fu) << 20;
    float f; memcpy(&f, &u, 4);
    return f * 0x1p120f;
}
__device__ inline unsigned f2e4_sw(float f) {
    f = fminf(f, 448.f);
    float y = f * 0x1p-120f;
    unsigned r; memcpy(&r, &y, 4);
    r = r + 0x7FFFFu + ((r >> 20) & 1u);
    return (r >> 20) & 0x7fu;
}
__device__ inline void acc_e4(float* a, unsigned w) {
#if __has_builtin(__builtin_amdgcn_cvt_pk_f32_fp8)
    f32x2 lo = __builtin_amdgcn_cvt_pk_f32_fp8(w, false);
    f32x2 hi = __builtin_amdgcn_cvt_pk_f32_fp8(w, true);
    a[0] += lo.x; a[1] += lo.y; a[2] += hi.x; a[3] += hi.y;
#else
    a[0] += e42f_sw(w);
    a[1] += e42f_sw(w >> 8);
    a[2] += e42f_sw(w >> 16);
    a[3] += e42f_sw(w >> 24);
#endif
}
__device__ inline unsigned pack_e4(float o0, float o1, float o2, float o3) {
#if __has_builtin(__builtin_amdgcn_cvt_pk_fp8_f32)
    unsigned pw = (unsigned)__builtin_amdgcn_cvt_pk_fp8_f32(
        fminf(o0, 448.f), fminf(o1, 448.f), 0, false);
    pw = (unsigned)__builtin_amdgcn_cvt_pk_fp8_f32(
        fminf(o2, 448.f), fminf(o3, 448.f), pw, true);
    return pw;
#else
    return f2e4_sw(o0) | (f2e4_sw(o1) << 8) | (f2e4_sw(o2) << 16) | (f2e4_sw(o3) << 24);
#endif
}

// ---------------- zero / init ----------------
__global__ void zero_kernel(float* __restrict__ p, int n) {
    int i = blockIdx.x * blockDim.x + threadIdx.x;
    if (i < n) p[i] = 0.f;
}
__global__ void init_gcur2(int* __restrict__ gA, int* __restrict__ gB, int P) {
    int i = blockIdx.x * blockDim.x + threadIdx.x;
    if (i < P) gA[i * GS] = i * SLOTS;
    else if (i < 2 * P) { int b = i - P; gB[b * GS] = b * SLOTS; }
}

// ---------------- phase 1: partition (R7 core, graph-batched grid) ----------------
// R12/R14 lesson: staging/LDS-sort confines writes to contiguous runs (L2-friendly);
// any random global write pattern across >4MB/XCD live windows thrashes to HBM.
__global__ void partition_edges(const int* __restrict__ srcA, const int* __restrict__ dstA,
                                int* __restrict__ gcurA, unsigned* __restrict__ stagedA,
                                const int* __restrict__ srcB, const int* __restrict__ dstB,
                                int* __restrict__ gcurB, unsigned* __restrict__ stagedB,
                                int gsplit, int E, int P) {
    __shared__ int h[4][MAXP];
    __shared__ int hbase[MAXP];
    __shared__ int cur[MAXP];
    __shared__ int gbase[MAXP];
    __shared__ unsigned sortedv[4096];
    __shared__ u16 bktid[4096];
    __shared__ int wsums[4];
    __shared__ int sTotal;
    const int* src; const int* dst; int* gcur; unsigned* staged;
    int bid = blockIdx.x;
    if (bid < gsplit) { src = srcA; dst = dstA; gcur = gcurA; staged = stagedA; }
    else { bid -= gsplit; src = srcB; dst = dstB; gcur = gcurB; staged = stagedB; }

    int t = threadIdx.x, wid = t >> 6, lane = t & 63;
    for (int i = t; i < 4 * MAXP; i += 256) (&h[0][0])[i] = 0;
    __syncthreads();

    int base = bid * 4096;
    int4 S[4], D[4];
#pragma unroll
    for (int r = 0; r < 4; r++) {
        int e = base + r * 1024 + t * 4;
        if (e + 3 < E) {
            S[r] = *(const int4*)(src + e);
            D[r] = *(const int4*)(dst + e);
        } else {
            int s0[4], d0[4];
            for (int j = 0; j < 4; j++) {
                int ee = e + j;
                s0[j] = (ee < E) ? src[ee] : -1;
                d0[j] = (ee < E) ? dst[ee] : -1;
            }
            S[r] = make_int4(s0[0], s0[1], s0[2], s0[3]);
            D[r] = make_int4(d0[0], d0[1], d0[2], d0[3]);
        }
        if (D[r].x >= 0) atomicAdd(&h[wid][D[r].x >> PSHIFT], 1);
        if (D[r].y >= 0) atomicAdd(&h[wid][D[r].y >> PSHIFT], 1);
        if (D[r].z >= 0) atomicAdd(&h[wid][D[r].z >> PSHIFT], 1);
        if (D[r].w >= 0) atomicAdd(&h[wid][D[r].w >> PSHIFT], 1);
    }
    __syncthreads();

    int b0 = 2 * t, b1 = 2 * t + 1;
    int t0 = (b0 < P) ? (h[0][b0] + h[1][b0] + h[2][b0] + h[3][b0]) : 0;
    int t1 = (b1 < P) ? (h[0][b1] + h[1][b1] + h[2][b1] + h[3][b1]) : 0;
    int s = t0 + t1;
    int incl = s;
#pragma unroll
    for (int off = 1; off < 64; off <<= 1) {
        int u = __shfl_up(incl, off, 64);
        if (lane >= off) incl += u;
    }
    if (lane == 63) wsums[wid] = incl;
    __syncthreads();
    int woff = 0;
#pragma unroll
    for (int w = 0; w < 4; w++) if (w < wid) woff += wsums[w];
    int excl = woff + incl - s;
    if (b0 < P) { hbase[b0] = excl;      cur[b0] = excl; }
    if (b1 < P) { hbase[b1] = excl + t0; cur[b1] = excl + t0; }
    if (b0 < P && t0) gbase[b0] = atomicAdd(&gcur[b0 * GS], t0);
    if (b1 < P && t1) gbase[b1] = atomicAdd(&gcur[b1 * GS], t1);
    if (t == 255) sTotal = excl + s;
    __syncthreads();

#pragma unroll
    for (int r = 0; r < 4; r++) {
        int ss[4] = { S[r].x, S[r].y, S[r].z, S[r].w };
        int dd[4] = { D[r].x, D[r].y, D[r].z, D[r].w };
#pragma unroll
        for (int j = 0; j < 4; j++) {
            int d = dd[j];
            if (d >= 0) {
                int bk = d >> PSHIFT;
                int pos = atomicAdd(&cur[bk], 1);
                sortedv[pos] = ((unsigned)(d & (NPB - 1)) << 17) | (unsigned)ss[j];
                bktid[pos]   = (u16)bk;
            }
        }
    }
    __syncthreads();

    int total = sTotal;
    for (int i = t; i < total; i += 256) {
        int bk = bktid[i];
        int addr = gbase[bk] + (i - hbase[bk]);
        if (addr < (bk + 1) * SLOTS)
            staged[addr] = sortedv[i];
    }
}

// ---------------- phase 2: bucket-count scan; block per graph ----------------
__global__ void scan_buckets(const int* __restrict__ gcurA, int* __restrict__ colbaseA,
                             int* __restrict__ rowptrA,
                             const int* __restrict__ gcurB, int* __restrict__ colbaseB,
                             int* __restrict__ rowptrB, int P, int N) {
    __shared__ int wsums[4];
    const int* gcur; int* colbase; int* rowptr;
    if (blockIdx.x == 0) { gcur = gcurA; colbase = colbaseA; rowptr = rowptrA; }
    else { gcur = gcurB; colbase = colbaseB; rowptr = rowptrB; }
    int t = threadIdx.x, wid = t >> 6, lane = t & 63;
    int b0 = 2 * t, b1 = 2 * t + 1;
    int c0 = 0, c1 = 0;
    if (b0 < P) { c0 = gcur[b0 * GS] - b0 * SLOTS; if (c0 > SLOTS) c0 = SLOTS; }
    if (b1 < P) { c1 = gcur[b1 * GS] - b1 * SLOTS; if (c1 > SLOTS) c1 = SLOTS; }
    int s = c0 + c1;
    int incl = s;
#pragma unroll
    for (int off = 1; off < 64; off <<= 1) {
        int u = __shfl_up(incl, off, 64);
        if (lane >= off) incl += u;
    }
    if (lane == 63) wsums[wid] = incl;
    __syncthreads();
    int woff = 0;
#pragma unroll
    for (int w = 0; w < 4; w++) if (w < wid) woff += wsums[w];
    int excl = woff + incl - s;
    if (b0 < P) colbase[b0] = excl;
    if (b1 < P) colbase[b1] = excl + c0;
    if (t == 255) {
        colbase[P] = excl + s;
        rowptr[N]  = excl + s;
    }
}

// ---------------- phase 3: per-bucket counting sort, LDS-staged writeout ---------
// R15: dst_local-only key (octile dead since fp8/L2), but KEEP the LDS sorted[]
// staging: placement scatters into LDS, writeout to col is CONTIGUOUS (R14's
// direct-global variant wrote 289MB to HBM: 50MB of live windows > 4MB/XCD L2).
__global__ void sort_bucket(const unsigned* __restrict__ stagedA, const int* __restrict__ gcurA,
                            const int* __restrict__ colbaseA, int* __restrict__ rowptrA,
                            int* __restrict__ colA,
                            const unsigned* __restrict__ stagedB, const int* __restrict__ gcurB,
                            const int* __restrict__ colbaseB, int* __restrict__ rowptrB,
                            int* __restrict__ colB,
                            int gsplit, int N) {
    __shared__ int cnt[NPB];            // 1 KB
    __shared__ int wsum[4];
    __shared__ int sorted[SLOTS];       // 68 KB
    const unsigned* staged; const int* gcur; const int* colbase; int* rowptr; int* col;
    int b = blockIdx.x;
    if (b < gsplit) { staged = stagedA; gcur = gcurA; colbase = colbaseA; rowptr = rowptrA; col = colA; }
    else { b -= gsplit; staged = stagedB; gcur = gcurB; colbase = colbaseB; rowptr = rowptrB; col = colB; }
    int t = threadIdx.x, lane = t & 63, wid = t >> 6;
    int sBeg = b * SLOTS;
    int sEnd = gcur[b * GS]; if (sEnd > sBeg + SLOTS) sEnd = sBeg + SLOTS;
    int total = sEnd - sBeg;
    int colStart = colbase[b];
    int nodeBase = b << PSHIFT;

    cnt[t] = 0;                          // NPB == 256 == blockDim
    __syncthreads();
    for (int i = sBeg + t; i < sEnd; i += 256)
        atomicAdd(&cnt[staged[i] >> 17], 1);
    __syncthreads();

    int myc = cnt[t];
    int incl = myc;
#pragma unroll
    for (int off = 1; off < 64; off <<= 1) {
        int u = __shfl_up(incl, off, 64);
        if (lane >= off) incl += u;
    }
    if (lane == 63) wsum[wid] = incl;
    __syncthreads();
    int woff = 0;
#pragma unroll
    for (int w = 0; w < 4; w++) if (w < wid) woff += wsum[w];
    int excl = woff + incl - myc;
    int node = nodeBase + t;
    if (node < N) rowptr[node] = colStart + excl;
    __syncthreads();
    cnt[t] = excl;                       // LDS placement cursor for node t
    __syncthreads();

    for (int i = sBeg + t; i < sEnd; i += 256) {
        unsigned w = staged[i];
        int pos = atomicAdd(&cnt[w >> 17], 1);
        sorted[pos] = (int)(w & 0x1FFFFu);
    }
    __syncthreads();
    for (int i = t; i < total; i += 256)   // contiguous coalesced writeout
        col[colStart + i] = sorted[i];
}

// ---------------- layer 0 fused: gather(d=1) + MLP -> fp8 out (graph-batched) -----
__global__ void mlp0_fused(const int* __restrict__ rowptrA, const int* __restrict__ colA,
                           const float* __restrict__ x0A, u8* __restrict__ outA,
                           const int* __restrict__ rowptrB, const int* __restrict__ colB,
                           const float* __restrict__ x0B, u8* __restrict__ outB,
                           const float* __restrict__ W1, const float* __restrict__ b1,
                           const float* __restrict__ W2, const float* __restrict__ b2,
                           int gsplit, int n) {
    __shared__ float sW1[HID], sb1[HID], sW2[HID * HID], sb2[HID];
    __shared__ int colbuf[COLBUF0];
    const int* rowptr; const int* col; const float* x0; u8* out;
    int bid = blockIdx.x;
    if (bid < gsplit) { rowptr = rowptrA; col = colA; x0 = x0A; out = outA; }
    else { bid -= gsplit; rowptr = rowptrB; col = colB; x0 = x0B; out = outB; }
    int t = threadIdx.x;
    if (t < HID) { sW1[t] = W1[t]; sb1[t] = b1[t]; sb2[t] = b2[t]; }
    for (int i = t; i < HID * HID; i += blockDim.x) sW2[i] = W2[i];

    int firstNode = bid * 64;
    int lastNode  = firstNode + 64; if (lastNode > n) lastNode = n;
    int blockStart = (firstNode < n) ? rowptr[firstNode] : 0;
    int blockEnd   = (firstNode < n) ? rowptr[lastNode] : 0;
    int stagedCnt = blockEnd - blockStart; if (stagedCnt > COLBUF0) stagedCnt = COLBUF0;
    for (int i = t; i < stagedCnt; i += 256) colbuf[i] = col[blockStart + i];
    __syncthreads();

    int node = firstNode + (t >> 2);
    int q    = t & 3;
    int lane = t & 63;
    int base = lane & ~3;
    bool active = node < n;

    float s = 0.f;
    if (active) {
        int beg = rowptr[node], end = rowptr[node + 1];
        int jSplit = blockStart + stagedCnt; if (jSplit > end) jSplit = end;
        int j = beg + q;
        for (; j + 12 < jSplit; j += 16) {
            int c0 = colbuf[j - blockStart];
            int c1 = colbuf[j + 4 - blockStart];
            int c2 = colbuf[j + 8 - blockStart];
            int c3 = colbuf[j + 12 - blockStart];
            s += x0[c0]; s += x0[c1]; s += x0[c2]; s += x0[c3];
        }
        for (; j < jSplit; j += 4) s += x0[colbuf[j - blockStart]];
        for (; j < end; j += 4) s += x0[col[j]];
    }
    s += __shfl_xor(s, 1, 64);
    s += __shfl_xor(s, 2, 64);
    float v = active ? (x0[node] + s) : 0.f;

    float h[8];
#pragma unroll
    for (int i = 0; i < 8; i++) h[i] = fmaxf(fmaf(v, sW1[q * 8 + i], sb1[q * 8 + i]), 0.f);
    float o[8];
#pragma unroll
    for (int i = 0; i < 8; i++) o[i] = sb2[q * 8 + i];
#pragma unroll
    for (int k = 0; k < HID; k++) {
        float hk = __shfl(h[k & 7], base | (k >> 3), 64);
#pragma unroll
        for (int i = 0; i < 8; i++) o[i] = fmaf(hk, sW2[k * HID + q * 8 + i], o[i]);
    }
    if (active) {
        unsigned w0 = pack_e4(fmaxf(o[0], 0.f), fmaxf(o[1], 0.f),
                              fmaxf(o[2], 0.f), fmaxf(o[3], 0.f));
        unsigned w1 = pack_e4(fmaxf(o[4], 0.f), fmaxf(o[5], 0.f),
                              fmaxf(o[6], 0.f), fmaxf(o[7], 0.f));
        uint2 pk = make_uint2(w0, w1);
        *(uint2*)(out + ((size_t)node << 5) + (q << 3)) = pk;
    }
}

// ---------------- hidden layer fused: fp8 gather + MLP (graph-batched) ----------
// R9 8-wide gather (R13 16-wide was null: per-CU MSHR cap, not per-wave).
template <bool REDUCE>
__global__ void mlp_fused(const int* __restrict__ rowptrA, const int* __restrict__ colA,
                          const u8* __restrict__ xinA, u8* __restrict__ xoutA,
                          float* __restrict__ hsumA,
                          const int* __restrict__ rowptrB, const int* __restrict__ colB,
                          const u8* __restrict__ xinB, u8* __restrict__ xoutB,
                          float* __restrict__ hsumB,
                          const float* __restrict__ W1, const float* __restrict__ b1,
                          const float* __restrict__ W2, const float* __restrict__ b2,
                          int gsplit, int n) {
    __shared__ float sW1[HID * HID], sb1[HID], sW2[HID * HID], sb2[HID];
    __shared__ int colbuf[COLBUF];
    __shared__ float red[4][HID];
    const int* rowptr; const int* col; const u8* xin; u8* xout; float* hsum;
    int bid = blockIdx.x;
    if (bid < gsplit) { rowptr = rowptrA; col = colA; xin = xinA; xout = xoutA; hsum = hsumA; }
    else { bid -= gsplit; rowptr = rowptrB; col = colB; xin = xinB; xout = xoutB; hsum = hsumB; }
    int t = threadIdx.x;
    for (int i = t; i < HID * HID; i += blockDim.x) { sW1[i] = W1[i]; sW2[i] = W2[i]; }
    if (t < HID) { sb1[t] = b1[t]; sb2[t] = b2[t]; }

    int firstNode = bid * 32;
    int lastNode  = firstNode + 32; if (lastNode > n) lastNode = n;
    int blockStart = (firstNode < n) ? rowptr[firstNode] : 0;
    int blockEnd   = (firstNode < n) ? rowptr[lastNode] : 0;
    int stagedCnt = blockEnd - blockStart; if (stagedCnt > COLBUF) stagedCnt = COLBUF;
    for (int i = t; i < stagedCnt; i += 256) colbuf[i] = col[blockStart + i];
    __syncthreads();

    int node = firstNode + (t >> 3);
    int q    = t & 7;
    int lane = t & 63;
    int base = lane & ~7;
    bool active = node < n;

    float va[4];
#pragma unroll
    for (int i = 0; i < 4; i++) va[i] = 0.f;
    if (active) {
        int beg = rowptr[node], end = rowptr[node + 1];
        const u8* xq = xin + (q << 2);
        float a0[4], a1[4], a2[4], a3[4];
#pragma unroll
        for (int i = 0; i < 4; i++) a0[i] = a1[i] = a2[i] = a3[i] = 0.f;
        {   // self term (eps = 0)
            unsigned w = *(const unsigned*)(xq + ((size_t)node << 5));
            acc_e4(a0, w);
        }
        int jSplit = blockStart + stagedCnt; if (jSplit > end) jSplit = end;
        int j = beg;
        for (; j + 8 <= jSplit; j += 8) {
            int lj = j - blockStart;
            int c0 = colbuf[lj+0], c1 = colbuf[lj+1], c2 = colbuf[lj+2], c3 = colbuf[lj+3];
            int c4 = colbuf[lj+4], c5 = colbuf[lj+5], c6 = colbuf[lj+6], c7 = colbuf[lj+7];
            unsigned w0 = *(const unsigned*)(xq + ((size_t)c0 << 5));
            unsigned w1 = *(const unsigned*)(xq + ((size_t)c1 << 5));
            unsigned w2 = *(const unsigned*)(xq + ((size_t)c2 << 5));
            unsigned w3 = *(const unsigned*)(xq + ((size_t)c3 << 5));
            unsigned w4 = *(const unsigned*)(xq + ((size_t)c4 << 5));
            unsigned w5 = *(const unsigned*)(xq + ((size_t)c5 << 5));
            unsigned w6 = *(const unsigned*)(xq + ((size_t)c6 << 5));
            unsigned w7 = *(const unsigned*)(xq + ((size_t)c7 << 5));
            acc_e4(a0, w0); acc_e4(a1, w1); acc_e4(a2, w2); acc_e4(a3, w3);
            acc_e4(a0, w4); acc_e4(a1, w5); acc_e4(a2, w6); acc_e4(a3, w7);
        }
        for (; j < jSplit; j++) {
            unsigned w = *(const unsigned*)(xq + ((size_t)colbuf[j - blockStart] << 5));
            acc_e4(a0, w);
        }
        for (; j < end; j++) {
            unsigned w = *(const unsigned*)(xq + ((size_t)col[j] << 5));
            acc_e4(a0, w);
        }
#pragma unroll
        for (int i = 0; i < 4; i++) va[i] = (a0[i] + a1[i]) + (a2[i] + a3[i]);
    }

    float h[4];
#pragma unroll
    for (int i = 0; i < 4; i++) h[i] = sb1[q * 4 + i];
#pragma unroll
    for (int k = 0; k < HID; k++) {
        float vk = __shfl(va[k & 3], base | (k >> 2), 64);
#pragma unroll
        for (int i = 0; i < 4; i++) h[i] = fmaf(vk, sW1[k * HID + q * 4 + i], h[i]);
    }
#pragma unroll
    for (int i = 0; i < 4; i++) h[i] = fmaxf(h[i], 0.f);

    float o[4];
#pragma unroll
    for (int i = 0; i < 4; i++) o[i] = sb2[q * 4 + i];
#pragma unroll
    for (int k = 0; k < HID; k++) {
        float hk = __shfl(h[k & 3], base | (k >> 2), 64);
#pragma unroll
        for (int i = 0; i < 4; i++) o[i] = fmaf(hk, sW2[k * HID + q * 4 + i], o[i]);
    }
#pragma unroll
    for (int i = 0; i < 4; i++) o[i] = fmaxf(o[i], 0.f);

    if (REDUCE) {
        if (!active) {
#pragma unroll
            for (int i = 0; i < 4; i++) o[i] = 0.f;
        }
#pragma unroll
        for (int i = 0; i < 4; i++) {
            float v = o[i];
            v += __shfl_xor(v, 8, 64);
            v += __shfl_xor(v, 16, 64);
            v += __shfl_xor(v, 32, 64);
            o[i] = v;
        }
        int wid = t >> 6;
        if (lane < 8) {
#pragma unroll
            for (int i = 0; i < 4; i++) red[wid][lane * 4 + i] = o[i];
        }
        __syncthreads();
        if (t < HID) {
            float s = red[0][t] + red[1][t] + red[2][t] + red[3][t];
            atomicAdd(&hsum[(blockIdx.x & (HS_ROWS - 1)) * (2 * HID) + t], s);
        }
    } else if (active) {
        unsigned pw = pack_e4(o[0], o[1], o[2], o[3]);
        *(unsigned*)(xout + ((size_t)node << 5) + (q << 2)) = pw;
    }
}

// ---------------- head ----------------
__global__ void head_kernel(const float* __restrict__ hsumP,
                            const float* __restrict__ Wc1, const float* __restrict__ bc1,
                            const float* __restrict__ Wc2, const float* __restrict__ bc2,
                            float* __restrict__ out) {
    __shared__ float hs[2 * HID];
    int t = threadIdx.x;
    if (t < 2 * HID) {
        float s = 0.f;
        for (int r = 0; r < HS_ROWS; r++) s += hsumP[r * (2 * HID) + t];
        hs[t] = s;
    }
    __syncthreads();
    float val = 0.f;
    if (t < HID) {
        float acc = bc1[t];
        for (int i = 0; i < 2 * HID; i++) acc = fmaf(hs[i], Wc1[i * HID + t], acc);
        val = fmaxf(acc, 0.f) * Wc2[t];
    }
    for (int off = 32; off >= 1; off >>= 1) val += __shfl_xor(val, off, 64);
    if (t == 0) out[0] = 1.f / (1.f + expf(-(val + bc2[0])));
}

extern "C" void kernel_launch(void* const* d_in, const int* in_sizes, int n_in,
                              void* d_out, int out_size, void* d_ws, size_t ws_size,
                              hipStream_t stream) {
    const float* xg[2] = { (const float*)d_in[0], (const float*)d_in[2] };
    const int*   eg[2] = { (const int*)d_in[1],   (const int*)d_in[3] };
    const float* W1[3] = { (const float*)d_in[4], (const float*)d_in[8],  (const float*)d_in[12] };
    const float* b1[3] = { (const float*)d_in[5], (const float*)d_in[9],  (const float*)d_in[13] };
    const float* W2[3] = { (const float*)d_in[6], (const float*)d_in[10], (const float*)d_in[14] };
    const float* b2[3] = { (const float*)d_in[7], (const float*)d_in[11], (const float*)d_in[15] };
    const float* Wc1 = (const float*)d_in[16];
    const float* bc1 = (const float*)d_in[17];
    const float* Wc2 = (const float*)d_in[18];
    const float* bc2 = (const float*)d_in[19];

    const int N = in_sizes[0];
    const int E = in_sizes[1] / 2;
    const int P = (N + NPB - 1) >> PSHIFT;   // 391 for N=100000

    const int TB = 256;
    dim3 blk(TB);
    int gE4k = (E + 4095) / 4096;
    int gN64 = (N + 63) / 64;
    int gN8  = (N + 31) / 32;

    // per-graph sizes (bytes)
    size_t szB    = (size_t)N * 32;                    // fp8 feature table
    size_t szRow  = (size_t)(N + 1) * 4;
    size_t szCol  = (size_t)E * 4;
    size_t szCb   = (size_t)(P + 1) * 4;
    size_t szGcur = (size_t)P * GS * 4;
    size_t szStg  = (size_t)P * SLOTS * 4;
    size_t szHsum = (size_t)HS_ROWS * 2 * HID * 4;
    size_t needBatched = 4 * szB + szHsum + 2 * (szRow + szCol + szCb + szGcur + szStg) + 4096;

    char* w = (char*)d_ws;
    auto take = [&](size_t sz) { char* p = w; w += (sz + 255) & ~(size_t)255; return p; };

    if (ws_size >= needBatched) {
        // ================= batched path: both graphs per dispatch =================
        u8*    B0[2]  = { (u8*)take(szB), (u8*)take(szB) };
        u8*    B1[2]  = { (u8*)take(szB), (u8*)take(szB) };
        float* hsumP  = (float*)take(szHsum);
        int*   rowp[2] = { (int*)take(szRow), (int*)take(szRow) };
        int*   col[2]  = { (int*)take(szCol), (int*)take(szCol) };
        int*   cb[2]   = { (int*)take(szCb), (int*)take(szCb) };
        int*   gc[2]   = { (int*)take(szGcur), (int*)take(szGcur) };
        unsigned* st[2] = { (unsigned*)take(szStg), (unsigned*)take(szStg) };

        zero_kernel<<<(HS_ROWS * 2 * HID + 255) / 256, 256, 0, stream>>>(hsumP, HS_ROWS * 2 * HID);
        init_gcur2<<<(2 * P + TB - 1) / TB, blk, 0, stream>>>(gc[0], gc[1], P);
        partition_edges<<<2 * gE4k, blk, 0, stream>>>(eg[0], eg[0] + E, gc[0], st[0],
                                                      eg[1], eg[1] + E, gc[1], st[1],
                                                      gE4k, E, P);
        scan_buckets<<<2, blk, 0, stream>>>(gc[0], cb[0], rowp[0], gc[1], cb[1], rowp[1], P, N);
        sort_bucket<<<2 * P, blk, 0, stream>>>(st[0], gc[0], cb[0], rowp[0], col[0],
                                               st[1], gc[1], cb[1], rowp[1], col[1], P, N);
        mlp0_fused<<<2 * gN64, blk, 0, stream>>>(rowp[0], col[0], xg[0], B0[0],
                                                 rowp[1], col[1], xg[1], B0[1],
                                                 W1[0], b1[0], W2[0], b2[0], gN64, N);
        mlp_fused<false><<<2 * gN8, blk, 0, stream>>>(rowp[0], col[0], B0[0], B1[0], nullptr,
                                                      rowp[1], col[1], B0[1], B1[1], nullptr,
                                                      W1[1], b1[1], W2[1], b2[1], gN8, N);
        mlp_fused<true><<<2 * gN8, blk, 0, stream>>>(rowp[0], col[0], B1[0], nullptr, hsumP,
                                                     rowp[1], col[1], B1[1], nullptr, hsumP + HID,
                                                     W1[2], b1[2], W2[2], b2[2], gN8, N);
        head_kernel<<<1, 64, 0, stream>>>(hsumP, Wc1, bc1, Wc2, bc2, (float*)d_out);
    } else {
        // ================= sequential fallback =================
        u8*    B0s    = (u8*)take(szB);
        u8*    B1s    = (u8*)take(szB);
        float* hsumP  = (float*)take(szHsum);
        int*   rowp   = (int*)take(szRow);
        int*   colp   = (int*)take(szCol);
        int*   cbp    = (int*)take(szCb);
        int*   gcp    = (int*)take(szGcur);
        unsigned* stp = (unsigned*)take(szStg);

        zero_kernel<<<(HS_ROWS * 2 * HID + 255) / 256, 256, 0, stream>>>(hsumP, HS_ROWS * 2 * HID);
        for (int g = 0; g < 2; g++) {
            const float* x0  = xg[g];
            const int*   src = eg[g];
            const int*   dst = src + E;
            init_gcur2<<<(P + TB - 1) / TB, blk, 0, stream>>>(gcp, gcp, P);
            partition_edges<<<gE4k, blk, 0, stream>>>(src, dst, gcp, stp,
                                                      src, dst, gcp, stp, gE4k, E, P);
            scan_buckets<<<1, blk, 0, stream>>>(gcp, cbp, rowp, gcp, cbp, rowp, P, N);
            sort_bucket<<<P, blk, 0, stream>>>(stp, gcp, cbp, rowp, colp,
                                               stp, gcp, cbp, rowp, colp, P, N);
            mlp0_fused<<<gN64, blk, 0, stream>>>(rowp, colp, x0, B0s,
                                                 rowp, colp, x0, B0s,
                                                 W1[0], b1[0], W2[0], b2[0], gN64, N);
            mlp_fused<false><<<gN8, blk, 0, stream>>>(rowp, colp, B0s, B1s, nullptr,
                                                      rowp, colp, B0s, B1s, nullptr,
                                                      W1[1], b1[1], W2[1], b2[1], gN8, N);
            mlp_fused<true><<<gN8, blk, 0, stream>>>(rowp, colp, B1s, nullptr, hsumP + g * HID,
                                                     rowp, colp, B1s, nullptr, hsumP + g * HID,
                                                     W1[2], b1[2], W2[2], b2[2], gN8, N);
        }
        head_kernel<<<1, 64, 0, stream>>>(hsumP, Wc1, bc1, Wc2, bc2, (float*)d_out);
    }
}